// Round 3
// baseline (2701.699 us; speedup 1.0000x reference)
//
#include <hip/hip_runtime.h>

// ---------------- problem constants (fixed by reference) ----------------
#define N0c 128000
#define N1c 256000
#define N2c 128000
#define BG  64        // graphs per batch
#define KNc 30
#define KEc 60
#define KTc 30
#define COC 16        // conv out channels
#define MLP_IN 1920   // 16*(30+60+30)
#define MLP_H 128

// ---------------------------------------------------------------------------
// K1: fused polynomial lift + dense GEMM.  Y[row] = [x, x*x] @ W   (64 -> 32)
// One thread per row; W staged in LDS (f32 [64][32]), broadcast reads.
// ---------------------------------------------------------------------------
__global__ __launch_bounds__(256) void gemm_lift(
    const float* __restrict__ X, int N, const float* __restrict__ W,
    float* __restrict__ Y)
{
    __shared__ float lw[2048];            // [64][32]
    const int tid = threadIdx.x;
    for (int i = tid; i < 2048; i += 256) lw[i] = W[i];
    __syncthreads();

    const int row = blockIdx.x * 256 + tid;
    if (row >= N) return;

    float x[64];
    const float4* p = reinterpret_cast<const float4*>(X + (size_t)row * 32);
    #pragma unroll
    for (int q = 0; q < 8; ++q) {
        float4 v = p[q];
        x[q*4+0] = v.x; x[q*4+1] = v.y; x[q*4+2] = v.z; x[q*4+3] = v.w;
    }
    #pragma unroll
    for (int i = 0; i < 32; ++i) x[32+i] = x[i] * x[i];

    const float4* lw4 = reinterpret_cast<const float4*>(lw);
    float4* yo = reinterpret_cast<float4*>(Y + (size_t)row * 32);
    #pragma unroll
    for (int j4 = 0; j4 < 8; ++j4) {
        float4 s = {0.f, 0.f, 0.f, 0.f};
        #pragma unroll
        for (int i = 0; i < 64; ++i) {
            float4 wf = lw4[i * 8 + j4];     // broadcast LDS read
            s.x = fmaf(x[i], wf.x, s.x);
            s.y = fmaf(x[i], wf.y, s.y);
            s.z = fmaf(x[i], wf.z, s.z);
            s.w = fmaf(x[i], wf.w, s.w);
        }
        yo[j4] = s;
    }
}

// ---------------------------------------------------------------------------
// K2: COO SPMM scatter: acc[row] += val * Y[col].  8 lanes per nnz, each lane
// handles one float4 chunk (coalesced 128B gather + 4 f32 atomics).
// f32 accumulation keeps sort keys within ~1e-6 of the np reference.
// ---------------------------------------------------------------------------
__global__ __launch_bounds__(256) void spmm_kernel(
    const int* __restrict__ rows, const int* __restrict__ cols,
    const float* __restrict__ vals,
    const float* __restrict__ Y, float* __restrict__ acc, int nnz)
{
    const int t = blockIdx.x * 256 + threadIdx.x;
    const int e = t >> 3, c = t & 7;
    if (e >= nnz) return;
    const int r = rows[e], col = cols[e];
    const float v = vals[e];
    const float4 yv = reinterpret_cast<const float4*>(Y + (size_t)col * 32)[c];
    float* a = acc + (size_t)r * 32 + c * 4;
    unsafeAtomicAdd(a + 0, v * yv.x);
    unsafeAtomicAdd(a + 1, v * yv.y);
    unsafeAtomicAdd(a + 2, v * yv.z);
    unsafeAtomicAdd(a + 3, v * yv.w);
}

// ---------------------------------------------------------------------------
// K3: per (graph, level): top-k by key = scale*relu(acc[:,31]) (desc order,
// tie -> lower index, matching jax.lax.top_k), gather pooled rows
// [X | scale*relu(acc)], then conv1d (kernel=stride=64) + relu -> xfeat.
// Keys live in registers (16 ULL/thread); wave shfl_xor + 4-entry LDS reduce.
// ---------------------------------------------------------------------------
__global__ __launch_bounds__(256) void topk_conv_kernel(
    const float* __restrict__ X0, const float* __restrict__ X1,
    const float* __restrict__ X2,
    const float* __restrict__ acc0, const float* __restrict__ acc1,
    const float* __restrict__ acc2,
    const float* __restrict__ CW0, const float* __restrict__ CW1,
    const float* __restrict__ CW2,
    float* __restrict__ xfeat)
{
    const int lvl = blockIdx.y;
    const int g   = blockIdx.x;
    int n, k, base; const float* X; const float* acc; const float* cw; float scale;
    if (lvl == 0)      { n = 2000; k = KNc; base = 0;              X = X0; acc = acc0; cw = CW0; scale = 0.5f; }
    else if (lvl == 1) { n = 4000; k = KEc; base = COC*KNc;        X = X1; acc = acc1; cw = CW1; scale = 1.0f/3.0f; }
    else               { n = 2000; k = KTc; base = COC*(KNc+KEc);  X = X2; acc = acc2; cw = CW2; scale = 0.5f; }

    __shared__ unsigned long long red[4];
    __shared__ float pooled[KEc][68];      // padded stride: no bank conflict
    __shared__ float wt[64][16];           // conv weights transposed [j][co]
    __shared__ int   sel[KEc];

    const int tid = threadIdx.x;
    const size_t rowbase = (size_t)g * n;

    // keys in registers: pack (key_bits << 32) | ~row.
    // -0.0 killed (kb=0 unless kv > 0); invalid slots = 0 (never selected).
    unsigned long long kreg[16];
    #pragma unroll
    for (int i = 0; i < 16; ++i) {
        const int r = i * 256 + tid;
        unsigned long long kk = 0ULL;
        if (r < n) {
            float kv = scale * fmaxf(acc[(rowbase + r) * 32 + 31], 0.0f);
            unsigned int kb = (kv > 0.0f) ? __float_as_uint(kv) : 0u;
            kk = ((unsigned long long)kb << 32) | (unsigned int)(~r);
        }
        kreg[i] = kk;
    }
    for (int i = tid; i < COC * 64; i += 256) {   // i = co*64 + j
        wt[i & 63][i >> 6] = cw[i];
    }

    // iterative arg-max selection (k <= 60 rounds)
    for (int it = 0; it < k; ++it) {
        unsigned long long m = 0ULL;
        #pragma unroll
        for (int i = 0; i < 16; ++i) m = kreg[i] > m ? kreg[i] : m;
        #pragma unroll
        for (int off = 32; off > 0; off >>= 1) {
            unsigned long long o = __shfl_xor(m, off, 64);
            m = o > m ? o : m;
        }
        if ((tid & 63) == 0) red[tid >> 6] = m;
        __syncthreads();
        unsigned long long m0 = red[0], m1 = red[1];
        unsigned long long m2 = red[2], m3 = red[3];
        unsigned long long ma = m0 > m1 ? m0 : m1;
        unsigned long long mb = m2 > m3 ? m2 : m3;
        unsigned long long mm = ma > mb ? ma : mb;
        if (tid == 0) sel[it] = (int)(~(unsigned int)mm);
        #pragma unroll
        for (int i = 0; i < 16; ++i) if (kreg[i] == mm) kreg[i] = 0ULL;  // remove
        __syncthreads();   // red[] reuse + sel[] visibility
    }

    // gather pooled rows: [X_orig(32) | scale*relu(acc)(32)]
    for (int t = tid; t < k * 32; t += 256) {
        const int r = t >> 5, i = t & 31;
        const size_t row = rowbase + sel[r];
        pooled[r][i]      = X[row * 32 + i];
        pooled[r][32 + i] = scale * fmaxf(acc[row * 32 + i], 0.0f);
    }
    __syncthreads();

    // conv1d kernel=stride=64: out[co, r] = relu(dot(pooled[r], w[co]))
    float* xo = xfeat + (size_t)g * MLP_IN + base;
    for (int t = tid; t < k * COC; t += 256) {
        const int r = t >> 4, co = t & 15;
        float s = 0.f;
        #pragma unroll
        for (int j = 0; j < 64; ++j) s = fmaf(pooled[r][j], wt[j][co], s);
        xo[co * k + r] = fmaxf(s, 0.f);
    }
}

// ---------------------------------------------------------------------------
// K4: tiny MLP: out = relu(x @ W1) @ W2, one block per graph.
// Output is FLOAT32 (reference returns f32; harness reads f32).
// ---------------------------------------------------------------------------
__global__ __launch_bounds__(128) void mlp_kernel(
    const float* __restrict__ xfeat, const float* __restrict__ W1,
    const float* __restrict__ W2, float* __restrict__ out)
{
    const int g = blockIdx.x, tid = threadIdx.x;
    __shared__ float xs[MLP_IN];
    __shared__ float hid[MLP_H];
    for (int i = tid; i < MLP_IN; i += 128) xs[i] = xfeat[(size_t)g * MLP_IN + i];
    __syncthreads();
    float s = 0.f;
    for (int i = 0; i < MLP_IN; ++i) s = fmaf(xs[i], W1[i * MLP_H + tid], s);
    hid[tid] = fmaxf(s, 0.f);
    __syncthreads();
    if (tid < 2) {
        float o = 0.f;
        #pragma unroll 8
        for (int h = 0; h < MLP_H; ++h) o = fmaf(hid[h], W2[h * 2 + tid], o);
        out[g * 2 + tid] = o;
    }
}

// ---------------------------------------------------------------------------
extern "C" void kernel_launch(void* const* d_in, const int* in_sizes, int n_in,
                              void* d_out, int out_size, void* d_ws, size_t ws_size,
                              hipStream_t stream)
{
    // --- inputs (setup_inputs dict order); float arrays are FLOAT32 ---
    const int*   L0r = (const int*)d_in[0];
    const int*   L0c = (const int*)d_in[1];
    const float* L0v = (const float*)d_in[2];
    const int*   L1r = (const int*)d_in[3];
    const int*   L1c = (const int*)d_in[4];
    const float* L1v = (const float*)d_in[5];
    const int*   L2r = (const int*)d_in[6];
    const int*   L2c = (const int*)d_in[7];
    const float* L2v = (const float*)d_in[8];
    const int*   D1r = (const int*)d_in[9];    // D1invB1    (N0 x N1)
    const int*   D1c = (const int*)d_in[10];
    const float* D1v = (const float*)d_in[11];
    const int*   D2r = (const int*)d_in[12];   // D2B1TD1inv (N1 x N0)
    const int*   D2c = (const int*)d_in[13];
    const float* D2v = (const float*)d_in[14];
    const int*   B2r = (const int*)d_in[15];   // B2TD2inv   (N2 x N1)
    const int*   B2c = (const int*)d_in[16];
    const float* B2v = (const float*)d_in[17];
    const int*   B3r = (const int*)d_in[18];   // B2D3       (N1 x N2)
    const int*   B3c = (const int*)d_in[19];
    const float* B3v = (const float*)d_in[20];
    const float* X0  = (const float*)d_in[21];
    const float* X1  = (const float*)d_in[22];
    const float* X2  = (const float*)d_in[23];
    const float* W_n2n = (const float*)d_in[24];
    const float* W_n2e = (const float*)d_in[25];
    const float* W_e2e = (const float*)d_in[26];
    const float* W_e2n = (const float*)d_in[27];
    const float* W_e2t = (const float*)d_in[28];
    const float* W_t2e = (const float*)d_in[29];
    const float* W_t2t = (const float*)d_in[30];
    const float* CWn = (const float*)d_in[31];
    const float* CWe = (const float*)d_in[32];
    const float* CWt = (const float*)d_in[33];
    const float* MW1 = (const float*)d_in[34];
    const float* MW2 = (const float*)d_in[35];

    const int nnzL0 = in_sizes[0],  nnzL1 = in_sizes[3],  nnzL2 = in_sizes[6];
    const int nnzD1 = in_sizes[9],  nnzD2 = in_sizes[12];
    const int nnzB2 = in_sizes[15], nnzB3 = in_sizes[18];

    // --- workspace (f32): single Y buffer reused, 7 sequential lift->spmm ---
    // total = (N1 + N0 + N1 + N2)*32 + 64*1920 floats  ~= 98.8 MB
    float* Y    = (float*)d_ws;
    float* acc0 = Y    + (size_t)N1c * 32;
    float* acc1 = acc0 + (size_t)N0c * 32;
    float* acc2 = acc1 + (size_t)N1c * 32;
    float* xfeat= acc2 + (size_t)N2c * 32;

    // zero the three accumulators (contiguous region)
    hipMemsetAsync(acc0, 0, (size_t)(N0c + N1c + N2c) * 32 * sizeof(float), stream);

    #define LIFT(Xp, Np, Wp)  gemm_lift<<<((Np) + 255) / 256, 256, 0, stream>>>((Xp), (Np), (Wp), Y)
    #define SPMM(rp, cp, vp, nz, accp) \
        spmm_kernel<<<((nz) * 8 + 255) / 256, 256, 0, stream>>>((rp), (cp), (vp), Y, (accp), (nz))

    LIFT(X0, N0c, W_n2n);  SPMM(L0r, L0c, L0v, nnzL0, acc0);   // n2n
    LIFT(X0, N0c, W_n2e);  SPMM(D2r, D2c, D2v, nnzD2, acc1);   // n2e
    LIFT(X1, N1c, W_e2e);  SPMM(L1r, L1c, L1v, nnzL1, acc1);   // e2e
    LIFT(X1, N1c, W_e2n);  SPMM(D1r, D1c, D1v, nnzD1, acc0);   // e2n
    LIFT(X1, N1c, W_e2t);  SPMM(B2r, B2c, B2v, nnzB2, acc2);   // e2t
    LIFT(X2, N2c, W_t2t);  SPMM(L2r, L2c, L2v, nnzL2, acc2);   // t2t
    LIFT(X2, N2c, W_t2e);  SPMM(B3r, B3c, B3v, nnzB3, acc1);   // t2e

    #undef LIFT
    #undef SPMM

    // sort-pool + conv1d (192 independent blocks), then MLP
    topk_conv_kernel<<<dim3(BG, 3), 256, 0, stream>>>(X0, X1, X2, acc0, acc1, acc2,
                                                      CWn, CWe, CWt, xfeat);
    mlp_kernel<<<BG, 128, 0, stream>>>(xfeat, MW1, MW2, (float*)d_out);
}

// Round 4
// 1182.595 us; speedup vs baseline: 2.2846x; 2.2846x over previous
//
#include <hip/hip_runtime.h>

// ---------------- problem constants (fixed by reference) ----------------
#define N0c 128000
#define N1c 256000
#define N2c 128000
#define BG  64        // graphs per batch
#define KNc 30
#define KEc 60
#define KTc 30
#define COC 16        // conv out channels
#define MLP_IN 1920   // 16*(30+60+30)
#define MLP_H 128

typedef unsigned long long u64;

// ---------------------------------------------------------------------------
// K1: fused polynomial lift + dense GEMM.  Y[row] = [x, x*x] @ W   (64 -> 32)
// ---------------------------------------------------------------------------
__global__ __launch_bounds__(256) void gemm_lift(
    const float* __restrict__ X, int N, const float* __restrict__ W,
    float* __restrict__ Y)
{
    __shared__ float lw[2048];            // [64][32]
    const int tid = threadIdx.x;
    for (int i = tid; i < 2048; i += 256) lw[i] = W[i];
    __syncthreads();

    const int row = blockIdx.x * 256 + tid;
    if (row >= N) return;

    float x[64];
    const float4* p = reinterpret_cast<const float4*>(X + (size_t)row * 32);
    #pragma unroll
    for (int q = 0; q < 8; ++q) {
        float4 v = p[q];
        x[q*4+0] = v.x; x[q*4+1] = v.y; x[q*4+2] = v.z; x[q*4+3] = v.w;
    }
    #pragma unroll
    for (int i = 0; i < 32; ++i) x[32+i] = x[i] * x[i];

    const float4* lw4 = reinterpret_cast<const float4*>(lw);
    float4* yo = reinterpret_cast<float4*>(Y + (size_t)row * 32);
    #pragma unroll
    for (int j4 = 0; j4 < 8; ++j4) {
        float4 s = {0.f, 0.f, 0.f, 0.f};
        #pragma unroll
        for (int i = 0; i < 64; ++i) {
            float4 wf = lw4[i * 8 + j4];     // broadcast LDS read
            s.x = fmaf(x[i], wf.x, s.x);
            s.y = fmaf(x[i], wf.y, s.y);
            s.z = fmaf(x[i], wf.z, s.z);
            s.w = fmaf(x[i], wf.w, s.w);
        }
        yo[j4] = s;
    }
}

// ================== CSR build (per matrix, rebuilt every call) ==============
// hist: ptr[r] = degree(r)  (no-return int atomics)
__global__ __launch_bounds__(256) void hist_kernel(
    const int* __restrict__ rows, int nnz, int* __restrict__ ptr)
{
    const int e = blockIdx.x * 256 + threadIdx.x;
    if (e < nnz) atomicAdd(&ptr[rows[e]], 1);
}

// scan stage A: per-block (1024-elem) sums of cnt[0..n)
__global__ __launch_bounds__(256) void scan_reduce(
    const int* __restrict__ cnt, int n, int* __restrict__ bsum)
{
    __shared__ int sm[256];
    const int b = blockIdx.x, tid = threadIdx.x;
    const int base = b * 1024 + tid * 4;
    int s = 0;
    if (base + 3 < n) {
        int4 v = *reinterpret_cast<const int4*>(cnt + base);
        s = v.x + v.y + v.z + v.w;
    } else {
        for (int i = 0; i < 4; ++i) if (base + i < n) s += cnt[base + i];
    }
    sm[tid] = s; __syncthreads();
    #pragma unroll
    for (int st = 128; st > 0; st >>= 1) {
        if (tid < st) sm[tid] += sm[tid + st];
        __syncthreads();
    }
    if (tid == 0) bsum[b] = sm[0];
}

// scan stage B: single-block exclusive scan of bsum[0..nb)  (nb <= 1024)
__global__ __launch_bounds__(1024) void scan_partials(int* __restrict__ bsum, int nb)
{
    __shared__ int sm[1024];
    const int tid = threadIdx.x;
    sm[tid] = (tid < nb) ? bsum[tid] : 0;
    __syncthreads();
    for (int off = 1; off < 1024; off <<= 1) {
        int v = (tid >= off) ? sm[tid - off] : 0;
        __syncthreads();
        sm[tid] += v;
        __syncthreads();
    }
    if (tid < nb) bsum[tid] = (tid == 0) ? 0 : sm[tid - 1];
}

// scan stage C: in-place exclusive scan of ptr[0..n) with block offsets
__global__ __launch_bounds__(256) void scan_write(
    int* __restrict__ ptr, int n, const int* __restrict__ bsum)
{
    __shared__ int sm[256];
    const int b = blockIdx.x, tid = threadIdx.x;
    const int base = b * 1024 + tid * 4;
    int v[4]; int s = 0;
    #pragma unroll
    for (int i = 0; i < 4; ++i) {
        v[i] = (base + i < n) ? ptr[base + i] : 0;
        s += v[i];
    }
    sm[tid] = s; __syncthreads();
    // inclusive Hillis-Steele over 256 thread sums
    for (int off = 1; off < 256; off <<= 1) {
        int t = (tid >= off) ? sm[tid - off] : 0;
        __syncthreads();
        sm[tid] += t;
        __syncthreads();
    }
    int run = bsum[b] + sm[tid] - s;   // exclusive offset for this thread
    #pragma unroll
    for (int i = 0; i < 4; ++i) {
        if (base + i < n) ptr[base + i] = run;
        run += v[i];
    }
}

// scatter: pairs[slot] = (val_bits<<32)|col, slot via fetch-add on ptr[r].
// Post-condition: ptr[r] = end offset of row r (destructive-cursor trick).
__global__ __launch_bounds__(256) void scatter_kernel(
    const int* __restrict__ rows, const int* __restrict__ cols,
    const float* __restrict__ vals, int nnz,
    int* __restrict__ ptr, u64* __restrict__ pairs)
{
    const int e = blockIdx.x * 256 + threadIdx.x;
    if (e >= nnz) return;
    const int pos = atomicAdd(&ptr[rows[e]], 1);
    pairs[pos] = ((u64)__float_as_uint(vals[e]) << 32) | (unsigned int)cols[e];
}

// ---------------------------------------------------------------------------
// K2': CSR gather SPMM.  8 lanes per row; lane j owns float4 chunk j of the
// 32-dim output.  Edges preloaded 8-at-a-time (coalesced) + shfl broadcast.
// acc written ONCE per row (STORE=1: overwrite; 0: accumulate).  No atomics.
// ---------------------------------------------------------------------------
__global__ __launch_bounds__(256) void spmm_csr(
    const int* __restrict__ ptr, const u64* __restrict__ pairs,
    const float* __restrict__ Y, float* __restrict__ acc, int R, int STORE)
{
    const int t = blockIdx.x * 256 + threadIdx.x;
    const int row = t >> 3;
    const int l8  = t & 7;
    if (row >= R) return;
    const int s = (row == 0) ? 0 : ptr[row - 1];
    const int e = ptr[row];

    const float4* Y4 = reinterpret_cast<const float4*>(Y);
    float4 a = {0.f, 0.f, 0.f, 0.f};
    for (int base = s; base < e; base += 8) {
        int m = e - base; if (m > 8) m = 8;
        u64 pk = (l8 < m) ? pairs[base + l8] : 0ULL;
        for (int j = 0; j < m; ++j) {
            const u64 pj = __shfl(pk, j, 8);           // broadcast within 8-group
            const int col   = (int)(unsigned int)(pj & 0xffffffffu);
            const float val = __uint_as_float((unsigned int)(pj >> 32));
            const float4 y = Y4[(size_t)col * 8 + l8];
            a.x = fmaf(val, y.x, a.x); a.y = fmaf(val, y.y, a.y);
            a.z = fmaf(val, y.z, a.z); a.w = fmaf(val, y.w, a.w);
        }
    }
    float4* ap = reinterpret_cast<float4*>(acc) + (size_t)row * 8 + l8;
    if (STORE) {
        *ap = a;
    } else {
        float4 o = *ap;
        o.x += a.x; o.y += a.y; o.z += a.z; o.w += a.w;
        *ap = o;
    }
}

// ---------------------------------------------------------------------------
// K2 (fallback): atomic COO SPMM (round-3 path, used if ws_size too small)
// ---------------------------------------------------------------------------
__global__ __launch_bounds__(256) void spmm_kernel(
    const int* __restrict__ rows, const int* __restrict__ cols,
    const float* __restrict__ vals,
    const float* __restrict__ Y, float* __restrict__ acc, int nnz)
{
    const int t = blockIdx.x * 256 + threadIdx.x;
    const int e = t >> 3, c = t & 7;
    if (e >= nnz) return;
    const int r = rows[e], col = cols[e];
    const float v = vals[e];
    const float4 yv = reinterpret_cast<const float4*>(Y + (size_t)col * 32)[c];
    float* a = acc + (size_t)r * 32 + c * 4;
    unsafeAtomicAdd(a + 0, v * yv.x);
    unsafeAtomicAdd(a + 1, v * yv.y);
    unsafeAtomicAdd(a + 2, v * yv.z);
    unsafeAtomicAdd(a + 3, v * yv.w);
}

// ---------------------------------------------------------------------------
// K3: per (graph, level) top-k + pooled gather + conv1d(kernel=stride=64)+relu
// ---------------------------------------------------------------------------
__global__ __launch_bounds__(256) void topk_conv_kernel(
    const float* __restrict__ X0, const float* __restrict__ X1,
    const float* __restrict__ X2,
    const float* __restrict__ acc0, const float* __restrict__ acc1,
    const float* __restrict__ acc2,
    const float* __restrict__ CW0, const float* __restrict__ CW1,
    const float* __restrict__ CW2,
    float* __restrict__ xfeat)
{
    const int lvl = blockIdx.y;
    const int g   = blockIdx.x;
    int n, k, base; const float* X; const float* acc; const float* cw; float scale;
    if (lvl == 0)      { n = 2000; k = KNc; base = 0;              X = X0; acc = acc0; cw = CW0; scale = 0.5f; }
    else if (lvl == 1) { n = 4000; k = KEc; base = COC*KNc;        X = X1; acc = acc1; cw = CW1; scale = 1.0f/3.0f; }
    else               { n = 2000; k = KTc; base = COC*(KNc+KEc);  X = X2; acc = acc2; cw = CW2; scale = 0.5f; }

    __shared__ u64 red[4];
    __shared__ float pooled[KEc][68];
    __shared__ float wt[64][16];
    __shared__ int   sel[KEc];

    const int tid = threadIdx.x;
    const size_t rowbase = (size_t)g * n;

    u64 kreg[16];
    #pragma unroll
    for (int i = 0; i < 16; ++i) {
        const int r = i * 256 + tid;
        u64 kk = 0ULL;
        if (r < n) {
            float kv = scale * fmaxf(acc[(rowbase + r) * 32 + 31], 0.0f);
            unsigned int kb = (kv > 0.0f) ? __float_as_uint(kv) : 0u;
            kk = ((u64)kb << 32) | (unsigned int)(~r);
        }
        kreg[i] = kk;
    }
    for (int i = tid; i < COC * 64; i += 256) wt[i & 63][i >> 6] = cw[i];

    for (int it = 0; it < k; ++it) {
        u64 m = 0ULL;
        #pragma unroll
        for (int i = 0; i < 16; ++i) m = kreg[i] > m ? kreg[i] : m;
        #pragma unroll
        for (int off = 32; off > 0; off >>= 1) {
            u64 o = __shfl_xor(m, off, 64);
            m = o > m ? o : m;
        }
        if ((tid & 63) == 0) red[tid >> 6] = m;
        __syncthreads();
        u64 m0 = red[0], m1 = red[1], m2 = red[2], m3 = red[3];
        u64 ma = m0 > m1 ? m0 : m1;
        u64 mb = m2 > m3 ? m2 : m3;
        u64 mm = ma > mb ? ma : mb;
        if (tid == 0) sel[it] = (int)(~(unsigned int)mm);
        #pragma unroll
        for (int i = 0; i < 16; ++i) if (kreg[i] == mm) kreg[i] = 0ULL;
        __syncthreads();
    }

    for (int t = tid; t < k * 32; t += 256) {
        const int r = t >> 5, i = t & 31;
        const size_t row = rowbase + sel[r];
        pooled[r][i]      = X[row * 32 + i];
        pooled[r][32 + i] = scale * fmaxf(acc[row * 32 + i], 0.0f);
    }
    __syncthreads();

    float* xo = xfeat + (size_t)g * MLP_IN + base;
    for (int t = tid; t < k * COC; t += 256) {
        const int r = t >> 4, co = t & 15;
        float s = 0.f;
        #pragma unroll
        for (int j = 0; j < 64; ++j) s = fmaf(pooled[r][j], wt[j][co], s);
        xo[co * k + r] = fmaxf(s, 0.f);
    }
}

// ---------------------------------------------------------------------------
// K4: tiny MLP: out = relu(x @ W1) @ W2, one block per graph.  Output f32.
// ---------------------------------------------------------------------------
__global__ __launch_bounds__(128) void mlp_kernel(
    const float* __restrict__ xfeat, const float* __restrict__ W1,
    const float* __restrict__ W2, float* __restrict__ out)
{
    const int g = blockIdx.x, tid = threadIdx.x;
    __shared__ float xs[MLP_IN];
    __shared__ float hid[MLP_H];
    for (int i = tid; i < MLP_IN; i += 128) xs[i] = xfeat[(size_t)g * MLP_IN + i];
    __syncthreads();
    float s = 0.f;
    for (int i = 0; i < MLP_IN; ++i) s = fmaf(xs[i], W1[i * MLP_H + tid], s);
    hid[tid] = fmaxf(s, 0.f);
    __syncthreads();
    if (tid < 2) {
        float o = 0.f;
        #pragma unroll 8
        for (int h = 0; h < MLP_H; ++h) o = fmaf(hid[h], W2[h * 2 + tid], o);
        out[g * 2 + tid] = o;
    }
}

// ---------------------------------------------------------------------------
extern "C" void kernel_launch(void* const* d_in, const int* in_sizes, int n_in,
                              void* d_out, int out_size, void* d_ws, size_t ws_size,
                              hipStream_t stream)
{
    const int*   L0r = (const int*)d_in[0];
    const int*   L0c = (const int*)d_in[1];
    const float* L0v = (const float*)d_in[2];
    const int*   L1r = (const int*)d_in[3];
    const int*   L1c = (const int*)d_in[4];
    const float* L1v = (const float*)d_in[5];
    const int*   L2r = (const int*)d_in[6];
    const int*   L2c = (const int*)d_in[7];
    const float* L2v = (const float*)d_in[8];
    const int*   D1r = (const int*)d_in[9];    // D1invB1    (N0 x N1)
    const int*   D1c = (const int*)d_in[10];
    const float* D1v = (const float*)d_in[11];
    const int*   D2r = (const int*)d_in[12];   // D2B1TD1inv (N1 x N0)
    const int*   D2c = (const int*)d_in[13];
    const float* D2v = (const float*)d_in[14];
    const int*   B2r = (const int*)d_in[15];   // B2TD2inv   (N2 x N1)
    const int*   B2c = (const int*)d_in[16];
    const float* B2v = (const float*)d_in[17];
    const int*   B3r = (const int*)d_in[18];   // B2D3       (N1 x N2)
    const int*   B3c = (const int*)d_in[19];
    const float* B3v = (const float*)d_in[20];
    const float* X0  = (const float*)d_in[21];
    const float* X1  = (const float*)d_in[22];
    const float* X2  = (const float*)d_in[23];
    const float* W_n2n = (const float*)d_in[24];
    const float* W_n2e = (const float*)d_in[25];
    const float* W_e2e = (const float*)d_in[26];
    const float* W_e2n = (const float*)d_in[27];
    const float* W_e2t = (const float*)d_in[28];
    const float* W_t2e = (const float*)d_in[29];
    const float* W_t2t = (const float*)d_in[30];
    const float* CWn = (const float*)d_in[31];
    const float* CWe = (const float*)d_in[32];
    const float* CWt = (const float*)d_in[33];
    const float* MW1 = (const float*)d_in[34];
    const float* MW2 = (const float*)d_in[35];

    const int nnzL0 = in_sizes[0],  nnzL1 = in_sizes[3],  nnzL2 = in_sizes[6];
    const int nnzD1 = in_sizes[9],  nnzD2 = in_sizes[12];
    const int nnzB2 = in_sizes[15], nnzB3 = in_sizes[18];

    int maxnnz = nnzL0;
    if (nnzL1 > maxnnz) maxnnz = nnzL1;
    if (nnzL2 > maxnnz) maxnnz = nnzL2;
    if (nnzD1 > maxnnz) maxnnz = nnzD1;
    if (nnzD2 > maxnnz) maxnnz = nnzD2;
    if (nnzB2 > maxnnz) maxnnz = nnzB2;
    if (nnzB3 > maxnnz) maxnnz = nnzB3;
    const size_t maxnnz_pad = ((size_t)maxnnz + 1) & ~(size_t)1;   // keep 16B align after

    // --- workspace layout (f32 base) ---
    float* Y    = (float*)d_ws;                 // N1*32
    float* acc0 = Y    + (size_t)N1c * 32;
    float* acc1 = acc0 + (size_t)N0c * 32;
    float* acc2 = acc1 + (size_t)N1c * 32;
    float* xfeat= acc2 + (size_t)N2c * 32;
    u64*   pairs= (u64*)(xfeat + (size_t)BG * MLP_IN);
    int*   ptr  = (int*)(pairs + maxnnz_pad);
    int*   bsum = ptr + (N1c + 1);

    const size_t base_bytes = (size_t)((char*)pairs - (char*)d_ws);
    const size_t need = base_bytes + maxnnz_pad * 8 + ((size_t)N1c + 1 + 1024) * 4;

    if (ws_size >= need) {
        // ================= CSR-gather path (no f32 atomics) =================
        #define BUILD_CSR(rp, cp, vp, nz, R)                                         \
            do {                                                                      \
                hipMemsetAsync(ptr, 0, ((size_t)(R) + 1) * sizeof(int), stream);      \
                hist_kernel<<<((nz) + 255) / 256, 256, 0, stream>>>((rp), (nz), ptr); \
                const int nb = ((R) + 1023) / 1024;                                   \
                scan_reduce<<<nb, 256, 0, stream>>>(ptr, (R), bsum);                  \
                scan_partials<<<1, 1024, 0, stream>>>(bsum, nb);                      \
                scan_write<<<nb, 256, 0, stream>>>(ptr, (R), bsum);                   \
                scatter_kernel<<<((nz) + 255) / 256, 256, 0, stream>>>(               \
                    (rp), (cp), (vp), (nz), ptr, pairs);                              \
            } while (0)
        #define LIFT(Xp, Np, Wp) \
            gemm_lift<<<((Np) + 255) / 256, 256, 0, stream>>>((Xp), (Np), (Wp), Y)
        #define SPMM_CSR(R, accp, store) \
            spmm_csr<<<(((R) * 8) + 255) / 256, 256, 0, stream>>>(ptr, pairs, Y, (accp), (R), (store))

        BUILD_CSR(L0r, L0c, L0v, nnzL0, N0c); LIFT(X0, N0c, W_n2n); SPMM_CSR(N0c, acc0, 1); // n2n
        BUILD_CSR(D2r, D2c, D2v, nnzD2, N1c); LIFT(X0, N0c, W_n2e); SPMM_CSR(N1c, acc1, 1); // n2e
        BUILD_CSR(L1r, L1c, L1v, nnzL1, N1c); LIFT(X1, N1c, W_e2e); SPMM_CSR(N1c, acc1, 0); // e2e
        BUILD_CSR(D1r, D1c, D1v, nnzD1, N0c); LIFT(X1, N1c, W_e2n); SPMM_CSR(N0c, acc0, 0); // e2n
        BUILD_CSR(B2r, B2c, B2v, nnzB2, N2c); LIFT(X1, N1c, W_e2t); SPMM_CSR(N2c, acc2, 1); // e2t
        BUILD_CSR(L2r, L2c, L2v, nnzL2, N2c); LIFT(X2, N2c, W_t2t); SPMM_CSR(N2c, acc2, 0); // t2t
        BUILD_CSR(B3r, B3c, B3v, nnzB3, N1c); LIFT(X2, N2c, W_t2e); SPMM_CSR(N1c, acc1, 0); // t2e

        #undef BUILD_CSR
        #undef LIFT
        #undef SPMM_CSR
    } else {
        // ================= fallback: atomic COO path (round-3) ==============
        hipMemsetAsync(acc0, 0, (size_t)(N0c + N1c + N2c) * 32 * sizeof(float), stream);
        #define LIFT(Xp, Np, Wp) \
            gemm_lift<<<((Np) + 255) / 256, 256, 0, stream>>>((Xp), (Np), (Wp), Y)
        #define SPMM(rp, cp, vp, nz, accp) \
            spmm_kernel<<<((nz) * 8 + 255) / 256, 256, 0, stream>>>((rp), (cp), (vp), Y, (accp), (nz))
        LIFT(X0, N0c, W_n2n);  SPMM(L0r, L0c, L0v, nnzL0, acc0);
        LIFT(X0, N0c, W_n2e);  SPMM(D2r, D2c, D2v, nnzD2, acc1);
        LIFT(X1, N1c, W_e2e);  SPMM(L1r, L1c, L1v, nnzL1, acc1);
        LIFT(X1, N1c, W_e2n);  SPMM(D1r, D1c, D1v, nnzD1, acc0);
        LIFT(X1, N1c, W_e2t);  SPMM(B2r, B2c, B2v, nnzB2, acc2);
        LIFT(X2, N2c, W_t2t);  SPMM(L2r, L2c, L2v, nnzL2, acc2);
        LIFT(X2, N2c, W_t2e);  SPMM(B3r, B3c, B3v, nnzB3, acc1);
        #undef LIFT
        #undef SPMM
    }

    topk_conv_kernel<<<dim3(BG, 3), 256, 0, stream>>>(X0, X1, X2, acc0, acc1, acc2,
                                                      CWn, CWe, CWt, xfeat);
    mlp_kernel<<<BG, 128, 0, stream>>>(xfeat, MW1, MW2, (float*)d_out);
}

// Round 5
// 978.937 us; speedup vs baseline: 2.7598x; 1.2080x over previous
//
#include <hip/hip_runtime.h>

// ---------------- problem constants (fixed by reference) ----------------
#define N0c 128000
#define N1c 256000
#define N2c 128000
#define BG  64        // graphs per batch
#define KNc 30
#define KEc 60
#define KTc 30
#define COC 16        // conv out channels
#define MLP_IN 1920   // 16*(30+60+30)
#define MLP_H 128

#define BINSHIFT 10           // 1024 rows per bin
#define BINROWS  1024
#define BDEPTH   16           // LDS staging depth per bin (pass 1)
#define BCAP     12288        // max entries per bin in pass 2 (mean ~8192)

typedef unsigned long long u64;
typedef unsigned int u32;

// ---------------------------------------------------------------------------
// K1: fused polynomial lift + dense GEMM.  Y[row] = [x, x*x] @ W   (64 -> 32)
// ---------------------------------------------------------------------------
__global__ __launch_bounds__(256) void gemm_lift(
    const float* __restrict__ X, int N, const float* __restrict__ W,
    float* __restrict__ Y)
{
    __shared__ float lw[2048];            // [64][32]
    const int tid = threadIdx.x;
    for (int i = tid; i < 2048; i += 256) lw[i] = W[i];
    __syncthreads();

    const int row = blockIdx.x * 256 + tid;
    if (row >= N) return;

    float x[64];
    const float4* p = reinterpret_cast<const float4*>(X + (size_t)row * 32);
    #pragma unroll
    for (int q = 0; q < 8; ++q) {
        float4 v = p[q];
        x[q*4+0] = v.x; x[q*4+1] = v.y; x[q*4+2] = v.z; x[q*4+3] = v.w;
    }
    #pragma unroll
    for (int i = 0; i < 32; ++i) x[32+i] = x[i] * x[i];

    const float4* lw4 = reinterpret_cast<const float4*>(lw);
    float4* yo = reinterpret_cast<float4*>(Y + (size_t)row * 32);
    #pragma unroll
    for (int j4 = 0; j4 < 8; ++j4) {
        float4 s = {0.f, 0.f, 0.f, 0.f};
        #pragma unroll
        for (int i = 0; i < 64; ++i) {
            float4 wf = lw4[i * 8 + j4];     // broadcast LDS read
            s.x = fmaf(x[i], wf.x, s.x);
            s.y = fmaf(x[i], wf.y, s.y);
            s.z = fmaf(x[i], wf.z, s.z);
            s.w = fmaf(x[i], wf.w, s.w);
        }
        yo[j4] = s;
    }
}

// ====================== binned CSR build (tier A) ===========================
// B1: per-block LDS histogram over bins, one global atomic per (block,bin)
__global__ __launch_bounds__(256) void bin_hist(
    const int* __restrict__ rows, int nnz, int epb, int nbins,
    int* __restrict__ bincnt)
{
    __shared__ int lh[256];
    const int tid = threadIdx.x;
    lh[tid] = 0;
    __syncthreads();
    const int base = blockIdx.x * epb;
    const int cnt = min(epb, nnz - base);
    for (int i = tid; i < cnt; i += 256)
        atomicAdd(&lh[rows[base + i] >> BINSHIFT], 1);
    __syncthreads();
    if (tid < nbins && lh[tid]) atomicAdd(&bincnt[tid], lh[tid]);
}

// B2: single-block exclusive scan over <=256 bin counts; init cursors
__global__ __launch_bounds__(256) void bin_scan(
    const int* __restrict__ bincnt, int nbins,
    int* __restrict__ binoff, int* __restrict__ gcur)
{
    __shared__ int sm[256];
    const int tid = threadIdx.x;
    const int v = (tid < nbins) ? bincnt[tid] : 0;
    sm[tid] = v;
    __syncthreads();
    for (int off = 1; off < 256; off <<= 1) {
        int t = (tid >= off) ? sm[tid - off] : 0;
        __syncthreads();
        sm[tid] += t;
        __syncthreads();
    }
    const int ex = sm[tid] - v;            // exclusive
    if (tid < nbins) { binoff[tid] = ex; gcur[tid] = ex; }
    if (tid == 255) binoff[nbins] = sm[255];
}

// B3: LDS-staged binned scatter of (val|col, row) -> tmpP/tmpR bin regions.
// Writes become contiguous ~depth*12B bursts -> no line thrash.
__global__ __launch_bounds__(256) void bin_scatter(
    const int* __restrict__ rows, const int* __restrict__ cols,
    const float* __restrict__ vals, int nnz, int epb, int nbins,
    int* __restrict__ gcur, u64* __restrict__ tmpP, u32* __restrict__ tmpR)
{
    __shared__ u64 bP[256 * BDEPTH];   // 32 KB
    __shared__ u32 bR[256 * BDEPTH];   // 16 KB
    __shared__ int lc[256];
    const int tid = threadIdx.x;
    lc[tid] = 0;
    __syncthreads();
    const int base = blockIdx.x * epb;
    const int cnt = min(epb, nnz - base);
    for (int i = tid; i < cnt; i += 256) {
        const int e = base + i;
        const int r = rows[e];
        const u64 pv = ((u64)__float_as_uint(vals[e]) << 32) | (u32)cols[e];
        const int b = r >> BINSHIFT;
        const int p = atomicAdd(&lc[b], 1);
        if (p < BDEPTH) {
            bP[b * BDEPTH + p] = pv;
            bR[b * BDEPTH + p] = (u32)r;
        } else {                               // rare spill (~1%)
            const int g = atomicAdd(&gcur[b], 1);
            tmpP[g] = pv; tmpR[g] = (u32)r;
        }
    }
    __syncthreads();
    if (tid < nbins) {
        int len = lc[tid]; if (len > BDEPTH) len = BDEPTH;
        if (len) {
            const int g = atomicAdd(&gcur[tid], len);
            for (int i = 0; i < len; ++i) {
                tmpP[g + i] = bP[tid * BDEPTH + i];
                tmpR[g + i] = bR[tid * BDEPTH + i];
            }
        }
    }
}

// B4: one block per bin: LDS row-hist + scan; emit ptr (inclusive row ends)
// and row-grouped pairs.  All global writes block-local -> L2 merges lines.
__global__ __launch_bounds__(256) void bin_build(
    const int* __restrict__ binoff, const u64* __restrict__ tmpP,
    const u32* __restrict__ tmpR, int R,
    u64* __restrict__ pairs, int* __restrict__ ptr)
{
    __shared__ unsigned short rl[BCAP];        // 24 KB
    __shared__ int h[BINROWS];                 // 4 KB
    __shared__ int cur[BINROWS];               // 4 KB
    __shared__ int sm[256];
    const int b = blockIdx.x, tid = threadIdx.x;
    const int base = binoff[b];
    int len = binoff[b + 1] - base;
    if (len > BCAP) len = BCAP;                // never expected

    for (int i = tid; i < BINROWS; i += 256) h[i] = 0;
    __syncthreads();
    for (int i = tid; i < len; i += 256) {
        const int r = (int)(tmpR[base + i] & (BINROWS - 1));
        rl[i] = (unsigned short)r;
        atomicAdd(&h[r], 1);
    }
    __syncthreads();

    // exclusive scan over 1024 row counts (4 per thread)
    const int i0 = tid * 4;
    const int a0 = h[i0], a1 = h[i0+1], a2 = h[i0+2], a3 = h[i0+3];
    const int s = a0 + a1 + a2 + a3;
    sm[tid] = s;
    __syncthreads();
    for (int off = 1; off < 256; off <<= 1) {
        int t = (tid >= off) ? sm[tid - off] : 0;
        __syncthreads();
        sm[tid] += t;
        __syncthreads();
    }
    const int run = sm[tid] - s;               // exclusive for this thread's rows
    cur[i0]   = run;
    cur[i0+1] = run + a0;
    cur[i0+2] = run + a0 + a1;
    cur[i0+3] = run + a0 + a1 + a2;
    const int rstart = b << BINSHIFT;
    if (rstart + i0     < R) ptr[rstart + i0    ] = base + run + a0;
    if (rstart + i0 + 1 < R) ptr[rstart + i0 + 1] = base + run + a0 + a1;
    if (rstart + i0 + 2 < R) ptr[rstart + i0 + 2] = base + run + a0 + a1 + a2;
    if (rstart + i0 + 3 < R) ptr[rstart + i0 + 3] = base + run + a0 + a1 + a2 + a3;
    __syncthreads();

    for (int i = tid; i < len; i += 256) {
        const int r = rl[i];
        const int pos = base + atomicAdd(&cur[r], 1);
        pairs[pos] = tmpP[base + i];           // block-local region write
    }
}

// ================== legacy CSR build kernels (tier B fallback) ==============
__global__ __launch_bounds__(256) void hist_kernel(
    const int* __restrict__ rows, int nnz, int* __restrict__ ptr)
{
    const int e = blockIdx.x * 256 + threadIdx.x;
    if (e < nnz) atomicAdd(&ptr[rows[e]], 1);
}

__global__ __launch_bounds__(256) void scan_reduce(
    const int* __restrict__ cnt, int n, int* __restrict__ bsum)
{
    __shared__ int sm[256];
    const int b = blockIdx.x, tid = threadIdx.x;
    const int base = b * 1024 + tid * 4;
    int s = 0;
    if (base + 3 < n) {
        int4 v = *reinterpret_cast<const int4*>(cnt + base);
        s = v.x + v.y + v.z + v.w;
    } else {
        for (int i = 0; i < 4; ++i) if (base + i < n) s += cnt[base + i];
    }
    sm[tid] = s; __syncthreads();
    #pragma unroll
    for (int st = 128; st > 0; st >>= 1) {
        if (tid < st) sm[tid] += sm[tid + st];
        __syncthreads();
    }
    if (tid == 0) bsum[b] = sm[0];
}

__global__ __launch_bounds__(1024) void scan_partials(int* __restrict__ bsum, int nb)
{
    __shared__ int sm[1024];
    const int tid = threadIdx.x;
    sm[tid] = (tid < nb) ? bsum[tid] : 0;
    __syncthreads();
    for (int off = 1; off < 1024; off <<= 1) {
        int v = (tid >= off) ? sm[tid - off] : 0;
        __syncthreads();
        sm[tid] += v;
        __syncthreads();
    }
    if (tid < nb) bsum[tid] = (tid == 0) ? 0 : sm[tid - 1];
}

__global__ __launch_bounds__(256) void scan_write(
    int* __restrict__ ptr, int n, const int* __restrict__ bsum)
{
    __shared__ int sm[256];
    const int b = blockIdx.x, tid = threadIdx.x;
    const int base = b * 1024 + tid * 4;
    int v[4]; int s = 0;
    #pragma unroll
    for (int i = 0; i < 4; ++i) {
        v[i] = (base + i < n) ? ptr[base + i] : 0;
        s += v[i];
    }
    sm[tid] = s; __syncthreads();
    for (int off = 1; off < 256; off <<= 1) {
        int t = (tid >= off) ? sm[tid - off] : 0;
        __syncthreads();
        sm[tid] += t;
        __syncthreads();
    }
    int run = bsum[b] + sm[tid] - s;
    #pragma unroll
    for (int i = 0; i < 4; ++i) {
        if (base + i < n) ptr[base + i] = run;
        run += v[i];
    }
}

__global__ __launch_bounds__(256) void scatter_kernel(
    const int* __restrict__ rows, const int* __restrict__ cols,
    const float* __restrict__ vals, int nnz,
    int* __restrict__ ptr, u64* __restrict__ pairs)
{
    const int e = blockIdx.x * 256 + threadIdx.x;
    if (e >= nnz) return;
    const int pos = atomicAdd(&ptr[rows[e]], 1);
    pairs[pos] = ((u64)__float_as_uint(vals[e]) << 32) | (u32)cols[e];
}

// ---------------------------------------------------------------------------
// K2': CSR gather SPMM.  8 lanes per row; lane j owns float4 chunk j of the
// 32-dim output.  No atomics; acc written once (STORE=1) or accumulated.
// ---------------------------------------------------------------------------
__global__ __launch_bounds__(256) void spmm_csr(
    const int* __restrict__ ptr, const u64* __restrict__ pairs,
    const float* __restrict__ Y, float* __restrict__ acc, int R, int STORE)
{
    const int t = blockIdx.x * 256 + threadIdx.x;
    const int row = t >> 3;
    const int l8  = t & 7;
    if (row >= R) return;
    const int s = (row == 0) ? 0 : ptr[row - 1];
    const int e = ptr[row];

    const float4* Y4 = reinterpret_cast<const float4*>(Y);
    float4 a = {0.f, 0.f, 0.f, 0.f};
    for (int base = s; base < e; base += 8) {
        int m = e - base; if (m > 8) m = 8;
        u64 pk = (l8 < m) ? pairs[base + l8] : 0ULL;
        for (int j = 0; j < m; ++j) {
            const u64 pj = __shfl(pk, j, 8);
            const int col   = (int)(u32)(pj & 0xffffffffu);
            const float val = __uint_as_float((u32)(pj >> 32));
            const float4 y = Y4[(size_t)col * 8 + l8];
            a.x = fmaf(val, y.x, a.x); a.y = fmaf(val, y.y, a.y);
            a.z = fmaf(val, y.z, a.z); a.w = fmaf(val, y.w, a.w);
        }
    }
    float4* ap = reinterpret_cast<float4*>(acc) + (size_t)row * 8 + l8;
    if (STORE) {
        *ap = a;
    } else {
        float4 o = *ap;
        o.x += a.x; o.y += a.y; o.z += a.z; o.w += a.w;
        *ap = o;
    }
}

// ---------------------------------------------------------------------------
// K2 (tier C fallback): atomic COO SPMM
// ---------------------------------------------------------------------------
__global__ __launch_bounds__(256) void spmm_kernel(
    const int* __restrict__ rows, const int* __restrict__ cols,
    const float* __restrict__ vals,
    const float* __restrict__ Y, float* __restrict__ acc, int nnz)
{
    const int t = blockIdx.x * 256 + threadIdx.x;
    const int e = t >> 3, c = t & 7;
    if (e >= nnz) return;
    const int r = rows[e], col = cols[e];
    const float v = vals[e];
    const float4 yv = reinterpret_cast<const float4*>(Y + (size_t)col * 32)[c];
    float* a = acc + (size_t)r * 32 + c * 4;
    unsafeAtomicAdd(a + 0, v * yv.x);
    unsafeAtomicAdd(a + 1, v * yv.y);
    unsafeAtomicAdd(a + 2, v * yv.z);
    unsafeAtomicAdd(a + 3, v * yv.w);
}

// ---------------------------------------------------------------------------
// K3: per (graph, level) top-k + pooled gather + conv1d(kernel=stride=64)+relu
// ---------------------------------------------------------------------------
__global__ __launch_bounds__(256) void topk_conv_kernel(
    const float* __restrict__ X0, const float* __restrict__ X1,
    const float* __restrict__ X2,
    const float* __restrict__ acc0, const float* __restrict__ acc1,
    const float* __restrict__ acc2,
    const float* __restrict__ CW0, const float* __restrict__ CW1,
    const float* __restrict__ CW2,
    float* __restrict__ xfeat)
{
    const int lvl = blockIdx.y;
    const int g   = blockIdx.x;
    int n, k, base; const float* X; const float* acc; const float* cw; float scale;
    if (lvl == 0)      { n = 2000; k = KNc; base = 0;              X = X0; acc = acc0; cw = CW0; scale = 0.5f; }
    else if (lvl == 1) { n = 4000; k = KEc; base = COC*KNc;        X = X1; acc = acc1; cw = CW1; scale = 1.0f/3.0f; }
    else               { n = 2000; k = KTc; base = COC*(KNc+KEc);  X = X2; acc = acc2; cw = CW2; scale = 0.5f; }

    __shared__ u64 red[4];
    __shared__ float pooled[KEc][68];
    __shared__ float wt[64][16];
    __shared__ int   sel[KEc];

    const int tid = threadIdx.x;
    const size_t rowbase = (size_t)g * n;

    u64 kreg[16];
    #pragma unroll
    for (int i = 0; i < 16; ++i) {
        const int r = i * 256 + tid;
        u64 kk = 0ULL;
        if (r < n) {
            float kv = scale * fmaxf(acc[(rowbase + r) * 32 + 31], 0.0f);
            u32 kb = (kv > 0.0f) ? __float_as_uint(kv) : 0u;
            kk = ((u64)kb << 32) | (u32)(~r);
        }
        kreg[i] = kk;
    }
    for (int i = tid; i < COC * 64; i += 256) wt[i & 63][i >> 6] = cw[i];

    for (int it = 0; it < k; ++it) {
        u64 m = 0ULL;
        #pragma unroll
        for (int i = 0; i < 16; ++i) m = kreg[i] > m ? kreg[i] : m;
        #pragma unroll
        for (int off = 32; off > 0; off >>= 1) {
            u64 o = __shfl_xor(m, off, 64);
            m = o > m ? o : m;
        }
        if ((tid & 63) == 0) red[tid >> 6] = m;
        __syncthreads();
        u64 m0 = red[0], m1 = red[1], m2 = red[2], m3 = red[3];
        u64 ma = m0 > m1 ? m0 : m1;
        u64 mb = m2 > m3 ? m2 : m3;
        u64 mm = ma > mb ? ma : mb;
        if (tid == 0) sel[it] = (int)(~(u32)mm);
        #pragma unroll
        for (int i = 0; i < 16; ++i) if (kreg[i] == mm) kreg[i] = 0ULL;
        __syncthreads();
    }

    for (int t = tid; t < k * 32; t += 256) {
        const int r = t >> 5, i = t & 31;
        const size_t row = rowbase + sel[r];
        pooled[r][i]      = X[row * 32 + i];
        pooled[r][32 + i] = scale * fmaxf(acc[row * 32 + i], 0.0f);
    }
    __syncthreads();

    float* xo = xfeat + (size_t)g * MLP_IN + base;
    for (int t = tid; t < k * COC; t += 256) {
        const int r = t >> 4, co = t & 15;
        float s = 0.f;
        #pragma unroll
        for (int j = 0; j < 64; ++j) s = fmaf(pooled[r][j], wt[j][co], s);
        xo[co * k + r] = fmaxf(s, 0.f);
    }
}

// ---------------------------------------------------------------------------
// K4: tiny MLP: out = relu(x @ W1) @ W2, one block per graph.  Output f32.
// ---------------------------------------------------------------------------
__global__ __launch_bounds__(128) void mlp_kernel(
    const float* __restrict__ xfeat, const float* __restrict__ W1,
    const float* __restrict__ W2, float* __restrict__ out)
{
    const int g = blockIdx.x, tid = threadIdx.x;
    __shared__ float xs[MLP_IN];
    __shared__ float hid[MLP_H];
    for (int i = tid; i < MLP_IN; i += 128) xs[i] = xfeat[(size_t)g * MLP_IN + i];
    __syncthreads();
    float s = 0.f;
    for (int i = 0; i < MLP_IN; ++i) s = fmaf(xs[i], W1[i * MLP_H + tid], s);
    hid[tid] = fmaxf(s, 0.f);
    __syncthreads();
    if (tid < 2) {
        float o = 0.f;
        #pragma unroll 8
        for (int h = 0; h < MLP_H; ++h) o = fmaf(hid[h], W2[h * 2 + tid], o);
        out[g * 2 + tid] = o;
    }
}

// ---------------------------------------------------------------------------
extern "C" void kernel_launch(void* const* d_in, const int* in_sizes, int n_in,
                              void* d_out, int out_size, void* d_ws, size_t ws_size,
                              hipStream_t stream)
{
    const int*   L0r = (const int*)d_in[0];
    const int*   L0c = (const int*)d_in[1];
    const float* L0v = (const float*)d_in[2];
    const int*   L1r = (const int*)d_in[3];
    const int*   L1c = (const int*)d_in[4];
    const float* L1v = (const float*)d_in[5];
    const int*   L2r = (const int*)d_in[6];
    const int*   L2c = (const int*)d_in[7];
    const float* L2v = (const float*)d_in[8];
    const int*   D1r = (const int*)d_in[9];    // D1invB1    (N0 x N1)
    const int*   D1c = (const int*)d_in[10];
    const float* D1v = (const float*)d_in[11];
    const int*   D2r = (const int*)d_in[12];   // D2B1TD1inv (N1 x N0)
    const int*   D2c = (const int*)d_in[13];
    const float* D2v = (const float*)d_in[14];
    const int*   B2r = (const int*)d_in[15];   // B2TD2inv   (N2 x N1)
    const int*   B2c = (const int*)d_in[16];
    const float* B2v = (const float*)d_in[17];
    const int*   B3r = (const int*)d_in[18];   // B2D3       (N1 x N2)
    const int*   B3c = (const int*)d_in[19];
    const float* B3v = (const float*)d_in[20];
    const float* X0  = (const float*)d_in[21];
    const float* X1  = (const float*)d_in[22];
    const float* X2  = (const float*)d_in[23];
    const float* W_n2n = (const float*)d_in[24];
    const float* W_n2e = (const float*)d_in[25];
    const float* W_e2e = (const float*)d_in[26];
    const float* W_e2n = (const float*)d_in[27];
    const float* W_e2t = (const float*)d_in[28];
    const float* W_t2e = (const float*)d_in[29];
    const float* W_t2t = (const float*)d_in[30];
    const float* CWn = (const float*)d_in[31];
    const float* CWe = (const float*)d_in[32];
    const float* CWt = (const float*)d_in[33];
    const float* MW1 = (const float*)d_in[34];
    const float* MW2 = (const float*)d_in[35];

    const int nnzL0 = in_sizes[0],  nnzL1 = in_sizes[3],  nnzL2 = in_sizes[6];
    const int nnzD1 = in_sizes[9],  nnzD2 = in_sizes[12];
    const int nnzB2 = in_sizes[15], nnzB3 = in_sizes[18];

    int maxnnz = nnzL0;
    if (nnzL1 > maxnnz) maxnnz = nnzL1;
    if (nnzL2 > maxnnz) maxnnz = nnzL2;
    if (nnzD1 > maxnnz) maxnnz = nnzD1;
    if (nnzD2 > maxnnz) maxnnz = nnzD2;
    if (nnzB2 > maxnnz) maxnnz = nnzB2;
    if (nnzB3 > maxnnz) maxnnz = nnzB3;

    // --- workspace layout (16B-aligned sections) ---
    char* wp = (char*)d_ws;
    #define WALLOC(ty, name, count) \
        ty* name = (ty*)wp; wp += (((size_t)(count) * sizeof(ty)) + 15) & ~(size_t)15;
    WALLOC(float, Y,     (size_t)N1c * 32)
    WALLOC(float, acc0,  (size_t)N0c * 32)
    WALLOC(float, acc1,  (size_t)N1c * 32)
    WALLOC(float, acc2,  (size_t)N2c * 32)
    WALLOC(float, xfeat, (size_t)BG * MLP_IN)
    WALLOC(u64,   pairs, (size_t)maxnnz)
    WALLOC(int,   ptr,   (size_t)N1c + 1)
    WALLOC(int,   bsum,  1024)
    const size_t need_B = (size_t)(wp - (char*)d_ws);
    WALLOC(u64,   tmpP,  (size_t)maxnnz)
    WALLOC(u32,   tmpR,  (size_t)maxnnz)
    WALLOC(int,   bincnt, 256)
    WALLOC(int,   binoff, 260)
    WALLOC(int,   gcur,   256)
    const size_t need_A = (size_t)(wp - (char*)d_ws);
    #undef WALLOC

    if (ws_size >= need_A) {
        // ============ tier A: binned two-pass CSR build, no row atomics ======
        #define BUILD_BIN(rp, cp, vp, nz, R)                                          \
            do {                                                                       \
                const int nbins = ((R) + BINROWS - 1) / BINROWS;                       \
                const int epb = nbins * 8;                                             \
                const int nblk = ((nz) + epb - 1) / epb;                               \
                hipMemsetAsync(bincnt, 0, (size_t)nbins * sizeof(int), stream);        \
                bin_hist<<<nblk, 256, 0, stream>>>((rp), (nz), epb, nbins, bincnt);    \
                bin_scan<<<1, 256, 0, stream>>>(bincnt, nbins, binoff, gcur);          \
                bin_scatter<<<nblk, 256, 0, stream>>>((rp), (cp), (vp), (nz), epb,     \
                                                      nbins, gcur, tmpP, tmpR);        \
                bin_build<<<nbins, 256, 0, stream>>>(binoff, tmpP, tmpR, (R),          \
                                                     pairs, ptr);                      \
            } while (0)
        #define LIFT(Xp, Np, Wp) \
            gemm_lift<<<((Np) + 255) / 256, 256, 0, stream>>>((Xp), (Np), (Wp), Y)
        #define SPMM_CSR(R, accp, store) \
            spmm_csr<<<(((R) * 8) + 255) / 256, 256, 0, stream>>>(ptr, pairs, Y, (accp), (R), (store))

        BUILD_BIN(L0r, L0c, L0v, nnzL0, N0c); LIFT(X0, N0c, W_n2n); SPMM_CSR(N0c, acc0, 1); // n2n
        BUILD_BIN(D2r, D2c, D2v, nnzD2, N1c); LIFT(X0, N0c, W_n2e); SPMM_CSR(N1c, acc1, 1); // n2e
        BUILD_BIN(L1r, L1c, L1v, nnzL1, N1c); LIFT(X1, N1c, W_e2e); SPMM_CSR(N1c, acc1, 0); // e2e
        BUILD_BIN(D1r, D1c, D1v, nnzD1, N0c); LIFT(X1, N1c, W_e2n); SPMM_CSR(N0c, acc0, 0); // e2n
        BUILD_BIN(B2r, B2c, B2v, nnzB2, N2c); LIFT(X1, N1c, W_e2t); SPMM_CSR(N2c, acc2, 1); // e2t
        BUILD_BIN(L2r, L2c, L2v, nnzL2, N2c); LIFT(X2, N2c, W_t2t); SPMM_CSR(N2c, acc2, 0); // t2t
        BUILD_BIN(B3r, B3c, B3v, nnzB3, N1c); LIFT(X2, N2c, W_t2e); SPMM_CSR(N1c, acc1, 0); // t2e

        #undef BUILD_BIN
        #undef LIFT
        #undef SPMM_CSR
    } else if (ws_size >= need_B) {
        // ============ tier B: round-4 CSR path (atomic scatter) ==============
        #define BUILD_CSR(rp, cp, vp, nz, R)                                         \
            do {                                                                      \
                hipMemsetAsync(ptr, 0, ((size_t)(R) + 1) * sizeof(int), stream);      \
                hist_kernel<<<((nz) + 255) / 256, 256, 0, stream>>>((rp), (nz), ptr); \
                const int nb = ((R) + 1023) / 1024;                                   \
                scan_reduce<<<nb, 256, 0, stream>>>(ptr, (R), bsum);                  \
                scan_partials<<<1, 1024, 0, stream>>>(bsum, nb);                      \
                scan_write<<<nb, 256, 0, stream>>>(ptr, (R), bsum);                   \
                scatter_kernel<<<((nz) + 255) / 256, 256, 0, stream>>>(               \
                    (rp), (cp), (vp), (nz), ptr, pairs);                              \
            } while (0)
        #define LIFT(Xp, Np, Wp) \
            gemm_lift<<<((Np) + 255) / 256, 256, 0, stream>>>((Xp), (Np), (Wp), Y)
        #define SPMM_CSR(R, accp, store) \
            spmm_csr<<<(((R) * 8) + 255) / 256, 256, 0, stream>>>(ptr, pairs, Y, (accp), (R), (store))

        BUILD_CSR(L0r, L0c, L0v, nnzL0, N0c); LIFT(X0, N0c, W_n2n); SPMM_CSR(N0c, acc0, 1);
        BUILD_CSR(D2r, D2c, D2v, nnzD2, N1c); LIFT(X0, N0c, W_n2e); SPMM_CSR(N1c, acc1, 1);
        BUILD_CSR(L1r, L1c, L1v, nnzL1, N1c); LIFT(X1, N1c, W_e2e); SPMM_CSR(N1c, acc1, 0);
        BUILD_CSR(D1r, D1c, D1v, nnzD1, N0c); LIFT(X1, N1c, W_e2n); SPMM_CSR(N0c, acc0, 0);
        BUILD_CSR(B2r, B2c, B2v, nnzB2, N2c); LIFT(X1, N1c, W_e2t); SPMM_CSR(N2c, acc2, 1);
        BUILD_CSR(L2r, L2c, L2v, nnzL2, N2c); LIFT(X2, N2c, W_t2t); SPMM_CSR(N2c, acc2, 0);
        BUILD_CSR(B3r, B3c, B3v, nnzB3, N1c); LIFT(X2, N2c, W_t2e); SPMM_CSR(N1c, acc1, 0);

        #undef BUILD_CSR
        #undef LIFT
        #undef SPMM_CSR
    } else {
        // ============ tier C: atomic COO path ================================
        hipMemsetAsync(acc0, 0, (size_t)(N0c + N1c + N2c) * 32 * sizeof(float), stream);
        #define LIFT(Xp, Np, Wp) \
            gemm_lift<<<((Np) + 255) / 256, 256, 0, stream>>>((Xp), (Np), (Wp), Y)
        #define SPMM(rp, cp, vp, nz, accp) \
            spmm_kernel<<<((nz) * 8 + 255) / 256, 256, 0, stream>>>((rp), (cp), (vp), Y, (accp), (nz))
        LIFT(X0, N0c, W_n2n);  SPMM(L0r, L0c, L0v, nnzL0, acc0);
        LIFT(X0, N0c, W_n2e);  SPMM(D2r, D2c, D2v, nnzD2, acc1);
        LIFT(X1, N1c, W_e2e);  SPMM(L1r, L1c, L1v, nnzL1, acc1);
        LIFT(X1, N1c, W_e2n);  SPMM(D1r, D1c, D1v, nnzD1, acc0);
        LIFT(X1, N1c, W_e2t);  SPMM(B2r, B2c, B2v, nnzB2, acc2);
        LIFT(X2, N2c, W_t2t);  SPMM(L2r, L2c, L2v, nnzL2, acc2);
        LIFT(X2, N2c, W_t2e);  SPMM(B3r, B3c, B3v, nnzB3, acc1);
        #undef LIFT
        #undef SPMM
    }

    topk_conv_kernel<<<dim3(BG, 3), 256, 0, stream>>>(X0, X1, X2, acc0, acc1, acc2,
                                                      CWn, CWe, CWt, xfeat);
    mlp_kernel<<<BG, 128, 0, stream>>>(xfeat, MW1, MW2, (float*)d_out);
}

// Round 6
// 937.737 us; speedup vs baseline: 2.8811x; 1.0439x over previous
//
#include <hip/hip_runtime.h>

// ---------------- problem constants (fixed by reference) ----------------
#define N0c 128000
#define N1c 256000
#define N2c 128000
#define BG  64        // graphs per batch
#define KNc 30
#define KEc 60
#define KTc 30
#define COC 16        // conv out channels
#define MLP_IN 1920   // 16*(30+60+30)
#define MLP_H 128
#define KSLICE 8      // MLP stage-1 k-split
#define KCH (MLP_IN / KSLICE)   // 240

#define BINSHIFT 10           // 1024 rows per bin
#define BINROWS  1024
#define BDEPTH   16           // LDS staging depth per bin (pass 1)
#define BCAP     12288        // max entries per bin in pass 2 (mean ~8192)

typedef unsigned long long u64;
typedef unsigned int u32;

// ---------------------------------------------------------------------------
// K1: fused polynomial lift + dense GEMM.  Y[row] = [x, x*x] @ W   (64 -> 32)
// ---------------------------------------------------------------------------
__global__ __launch_bounds__(256) void gemm_lift(
    const float* __restrict__ X, int N, const float* __restrict__ W,
    float* __restrict__ Y)
{
    __shared__ float lw[2048];            // [64][32]
    const int tid = threadIdx.x;
    for (int i = tid; i < 2048; i += 256) lw[i] = W[i];
    __syncthreads();

    const int row = blockIdx.x * 256 + tid;
    if (row >= N) return;

    float x[64];
    const float4* p = reinterpret_cast<const float4*>(X + (size_t)row * 32);
    #pragma unroll
    for (int q = 0; q < 8; ++q) {
        float4 v = p[q];
        x[q*4+0] = v.x; x[q*4+1] = v.y; x[q*4+2] = v.z; x[q*4+3] = v.w;
    }
    #pragma unroll
    for (int i = 0; i < 32; ++i) x[32+i] = x[i] * x[i];

    const float4* lw4 = reinterpret_cast<const float4*>(lw);
    float4* yo = reinterpret_cast<float4*>(Y + (size_t)row * 32);
    #pragma unroll
    for (int j4 = 0; j4 < 8; ++j4) {
        float4 s = {0.f, 0.f, 0.f, 0.f};
        #pragma unroll
        for (int i = 0; i < 64; ++i) {
            float4 wf = lw4[i * 8 + j4];     // broadcast LDS read
            s.x = fmaf(x[i], wf.x, s.x);
            s.y = fmaf(x[i], wf.y, s.y);
            s.z = fmaf(x[i], wf.z, s.z);
            s.w = fmaf(x[i], wf.w, s.w);
        }
        yo[j4] = s;
    }
}

// ====================== binned CSR build (tier A) ===========================
// B1: per-block LDS histogram over bins, one global atomic per (block,bin)
__global__ __launch_bounds__(256) void bin_hist(
    const int* __restrict__ rows, int nnz, int epb, int nbins,
    int* __restrict__ bincnt)
{
    __shared__ int lh[256];
    const int tid = threadIdx.x;
    lh[tid] = 0;
    __syncthreads();
    const int base = blockIdx.x * epb;
    const int cnt = min(epb, nnz - base);
    for (int i = tid; i < cnt; i += 256)
        atomicAdd(&lh[rows[base + i] >> BINSHIFT], 1);
    __syncthreads();
    if (tid < nbins && lh[tid]) atomicAdd(&bincnt[tid], lh[tid]);
}

// B2: single-block exclusive scan over <=256 bin counts; init cursors
__global__ __launch_bounds__(256) void bin_scan(
    const int* __restrict__ bincnt, int nbins,
    int* __restrict__ binoff, int* __restrict__ gcur)
{
    __shared__ int sm[256];
    const int tid = threadIdx.x;
    const int v = (tid < nbins) ? bincnt[tid] : 0;
    sm[tid] = v;
    __syncthreads();
    for (int off = 1; off < 256; off <<= 1) {
        int t = (tid >= off) ? sm[tid - off] : 0;
        __syncthreads();
        sm[tid] += t;
        __syncthreads();
    }
    const int ex = sm[tid] - v;            // exclusive
    if (tid < nbins) { binoff[tid] = ex; gcur[tid] = ex; }
    if (tid == 255) binoff[nbins] = sm[255];
}

// B3: LDS-staged binned scatter of (val|col, row) -> tmpP/tmpR bin regions.
__global__ __launch_bounds__(256) void bin_scatter(
    const int* __restrict__ rows, const int* __restrict__ cols,
    const float* __restrict__ vals, int nnz, int epb, int nbins,
    int* __restrict__ gcur, u64* __restrict__ tmpP, u32* __restrict__ tmpR)
{
    __shared__ u64 bP[256 * BDEPTH];   // 32 KB
    __shared__ u32 bR[256 * BDEPTH];   // 16 KB
    __shared__ int lc[256];
    const int tid = threadIdx.x;
    lc[tid] = 0;
    __syncthreads();
    const int base = blockIdx.x * epb;
    const int cnt = min(epb, nnz - base);
    for (int i = tid; i < cnt; i += 256) {
        const int e = base + i;
        const int r = rows[e];
        const u64 pv = ((u64)__float_as_uint(vals[e]) << 32) | (u32)cols[e];
        const int b = r >> BINSHIFT;
        const int p = atomicAdd(&lc[b], 1);
        if (p < BDEPTH) {
            bP[b * BDEPTH + p] = pv;
            bR[b * BDEPTH + p] = (u32)r;
        } else {                               // rare spill (~1%)
            const int g = atomicAdd(&gcur[b], 1);
            tmpP[g] = pv; tmpR[g] = (u32)r;
        }
    }
    __syncthreads();
    if (tid < nbins) {
        int len = lc[tid]; if (len > BDEPTH) len = BDEPTH;
        if (len) {
            const int g = atomicAdd(&gcur[tid], len);
            for (int i = 0; i < len; ++i) {
                tmpP[g + i] = bP[tid * BDEPTH + i];
                tmpR[g + i] = bR[tid * BDEPTH + i];
            }
        }
    }
}

// B4: one block per bin: LDS row-hist + scan; emit ptr (inclusive row ends)
// and row-grouped pairs.
__global__ __launch_bounds__(256) void bin_build(
    const int* __restrict__ binoff, const u64* __restrict__ tmpP,
    const u32* __restrict__ tmpR, int R,
    u64* __restrict__ pairs, int* __restrict__ ptr)
{
    __shared__ unsigned short rl[BCAP];        // 24 KB
    __shared__ int h[BINROWS];                 // 4 KB
    __shared__ int cur[BINROWS];               // 4 KB
    __shared__ int sm[256];
    const int b = blockIdx.x, tid = threadIdx.x;
    const int base = binoff[b];
    int len = binoff[b + 1] - base;
    if (len > BCAP) len = BCAP;                // never expected

    for (int i = tid; i < BINROWS; i += 256) h[i] = 0;
    __syncthreads();
    for (int i = tid; i < len; i += 256) {
        const int r = (int)(tmpR[base + i] & (BINROWS - 1));
        rl[i] = (unsigned short)r;
        atomicAdd(&h[r], 1);
    }
    __syncthreads();

    const int i0 = tid * 4;
    const int a0 = h[i0], a1 = h[i0+1], a2 = h[i0+2], a3 = h[i0+3];
    const int s = a0 + a1 + a2 + a3;
    sm[tid] = s;
    __syncthreads();
    for (int off = 1; off < 256; off <<= 1) {
        int t = (tid >= off) ? sm[tid - off] : 0;
        __syncthreads();
        sm[tid] += t;
        __syncthreads();
    }
    const int run = sm[tid] - s;
    cur[i0]   = run;
    cur[i0+1] = run + a0;
    cur[i0+2] = run + a0 + a1;
    cur[i0+3] = run + a0 + a1 + a2;
    const int rstart = b << BINSHIFT;
    if (rstart + i0     < R) ptr[rstart + i0    ] = base + run + a0;
    if (rstart + i0 + 1 < R) ptr[rstart + i0 + 1] = base + run + a0 + a1;
    if (rstart + i0 + 2 < R) ptr[rstart + i0 + 2] = base + run + a0 + a1 + a2;
    if (rstart + i0 + 3 < R) ptr[rstart + i0 + 3] = base + run + a0 + a1 + a2 + a3;
    __syncthreads();

    for (int i = tid; i < len; i += 256) {
        const int r = rl[i];
        const int pos = base + atomicAdd(&cur[r], 1);
        pairs[pos] = tmpP[base + i];
    }
}

// ================== legacy CSR build kernels (tier B fallback) ==============
__global__ __launch_bounds__(256) void hist_kernel(
    const int* __restrict__ rows, int nnz, int* __restrict__ ptr)
{
    const int e = blockIdx.x * 256 + threadIdx.x;
    if (e < nnz) atomicAdd(&ptr[rows[e]], 1);
}

__global__ __launch_bounds__(256) void scan_reduce(
    const int* __restrict__ cnt, int n, int* __restrict__ bsum)
{
    __shared__ int sm[256];
    const int b = blockIdx.x, tid = threadIdx.x;
    const int base = b * 1024 + tid * 4;
    int s = 0;
    if (base + 3 < n) {
        int4 v = *reinterpret_cast<const int4*>(cnt + base);
        s = v.x + v.y + v.z + v.w;
    } else {
        for (int i = 0; i < 4; ++i) if (base + i < n) s += cnt[base + i];
    }
    sm[tid] = s; __syncthreads();
    #pragma unroll
    for (int st = 128; st > 0; st >>= 1) {
        if (tid < st) sm[tid] += sm[tid + st];
        __syncthreads();
    }
    if (tid == 0) bsum[b] = sm[0];
}

__global__ __launch_bounds__(1024) void scan_partials(int* __restrict__ bsum, int nb)
{
    __shared__ int sm[1024];
    const int tid = threadIdx.x;
    sm[tid] = (tid < nb) ? bsum[tid] : 0;
    __syncthreads();
    for (int off = 1; off < 1024; off <<= 1) {
        int v = (tid >= off) ? sm[tid - off] : 0;
        __syncthreads();
        sm[tid] += v;
        __syncthreads();
    }
    if (tid < nb) bsum[tid] = (tid == 0) ? 0 : sm[tid - 1];
}

__global__ __launch_bounds__(256) void scan_write(
    int* __restrict__ ptr, int n, const int* __restrict__ bsum)
{
    __shared__ int sm[256];
    const int b = blockIdx.x, tid = threadIdx.x;
    const int base = b * 1024 + tid * 4;
    int v[4]; int s = 0;
    #pragma unroll
    for (int i = 0; i < 4; ++i) {
        v[i] = (base + i < n) ? ptr[base + i] : 0;
        s += v[i];
    }
    sm[tid] = s; __syncthreads();
    for (int off = 1; off < 256; off <<= 1) {
        int t = (tid >= off) ? sm[tid - off] : 0;
        __syncthreads();
        sm[tid] += t;
        __syncthreads();
    }
    int run = bsum[b] + sm[tid] - s;
    #pragma unroll
    for (int i = 0; i < 4; ++i) {
        if (base + i < n) ptr[base + i] = run;
        run += v[i];
    }
}

__global__ __launch_bounds__(256) void scatter_kernel(
    const int* __restrict__ rows, const int* __restrict__ cols,
    const float* __restrict__ vals, int nnz,
    int* __restrict__ ptr, u64* __restrict__ pairs)
{
    const int e = blockIdx.x * 256 + threadIdx.x;
    if (e >= nnz) return;
    const int pos = atomicAdd(&ptr[rows[e]], 1);
    pairs[pos] = ((u64)__float_as_uint(vals[e]) << 32) | (u32)cols[e];
}

// ---------------------------------------------------------------------------
// K2': CSR gather SPMM.  8 lanes per row; lane j owns float4 chunk j.
// ---------------------------------------------------------------------------
__global__ __launch_bounds__(256) void spmm_csr(
    const int* __restrict__ ptr, const u64* __restrict__ pairs,
    const float* __restrict__ Y, float* __restrict__ acc, int R, int STORE)
{
    const int t = blockIdx.x * 256 + threadIdx.x;
    const int row = t >> 3;
    const int l8  = t & 7;
    if (row >= R) return;
    const int s = (row == 0) ? 0 : ptr[row - 1];
    const int e = ptr[row];

    const float4* Y4 = reinterpret_cast<const float4*>(Y);
    float4 a = {0.f, 0.f, 0.f, 0.f};
    for (int base = s; base < e; base += 8) {
        int m = e - base; if (m > 8) m = 8;
        u64 pk = (l8 < m) ? pairs[base + l8] : 0ULL;
        for (int j = 0; j < m; ++j) {
            const u64 pj = __shfl(pk, j, 8);
            const int col   = (int)(u32)(pj & 0xffffffffu);
            const float val = __uint_as_float((u32)(pj >> 32));
            const float4 y = Y4[(size_t)col * 8 + l8];
            a.x = fmaf(val, y.x, a.x); a.y = fmaf(val, y.y, a.y);
            a.z = fmaf(val, y.z, a.z); a.w = fmaf(val, y.w, a.w);
        }
    }
    float4* ap = reinterpret_cast<float4*>(acc) + (size_t)row * 8 + l8;
    if (STORE) {
        *ap = a;
    } else {
        float4 o = *ap;
        o.x += a.x; o.y += a.y; o.z += a.z; o.w += a.w;
        *ap = o;
    }
}

// ---------------------------------------------------------------------------
// K2 (tier C fallback): atomic COO SPMM
// ---------------------------------------------------------------------------
__global__ __launch_bounds__(256) void spmm_kernel(
    const int* __restrict__ rows, const int* __restrict__ cols,
    const float* __restrict__ vals,
    const float* __restrict__ Y, float* __restrict__ acc, int nnz)
{
    const int t = blockIdx.x * 256 + threadIdx.x;
    const int e = t >> 3, c = t & 7;
    if (e >= nnz) return;
    const int r = rows[e], col = cols[e];
    const float v = vals[e];
    const float4 yv = reinterpret_cast<const float4*>(Y + (size_t)col * 32)[c];
    float* a = acc + (size_t)r * 32 + c * 4;
    unsafeAtomicAdd(a + 0, v * yv.x);
    unsafeAtomicAdd(a + 1, v * yv.y);
    unsafeAtomicAdd(a + 2, v * yv.z);
    unsafeAtomicAdd(a + 3, v * yv.w);
}

// ---------------------------------------------------------------------------
// K3: per (graph, level) top-k + pooled gather + conv1d(kernel=stride=64)+relu
// ---------------------------------------------------------------------------
__global__ __launch_bounds__(256) void topk_conv_kernel(
    const float* __restrict__ X0, const float* __restrict__ X1,
    const float* __restrict__ X2,
    const float* __restrict__ acc0, const float* __restrict__ acc1,
    const float* __restrict__ acc2,
    const float* __restrict__ CW0, const float* __restrict__ CW1,
    const float* __restrict__ CW2,
    float* __restrict__ xfeat)
{
    const int lvl = blockIdx.y;
    const int g   = blockIdx.x;
    int n, k, base; const float* X; const float* acc; const float* cw; float scale;
    if (lvl == 0)      { n = 2000; k = KNc; base = 0;              X = X0; acc = acc0; cw = CW0; scale = 0.5f; }
    else if (lvl == 1) { n = 4000; k = KEc; base = COC*KNc;        X = X1; acc = acc1; cw = CW1; scale = 1.0f/3.0f; }
    else               { n = 2000; k = KTc; base = COC*(KNc+KEc);  X = X2; acc = acc2; cw = CW2; scale = 0.5f; }

    __shared__ u64 red[4];
    __shared__ float pooled[KEc][68];
    __shared__ float wt[64][16];
    __shared__ int   sel[KEc];

    const int tid = threadIdx.x;
    const size_t rowbase = (size_t)g * n;

    u64 kreg[16];
    #pragma unroll
    for (int i = 0; i < 16; ++i) {
        const int r = i * 256 + tid;
        u64 kk = 0ULL;
        if (r < n) {
            float kv = scale * fmaxf(acc[(rowbase + r) * 32 + 31], 0.0f);
            u32 kb = (kv > 0.0f) ? __float_as_uint(kv) : 0u;
            kk = ((u64)kb << 32) | (u32)(~r);
        }
        kreg[i] = kk;
    }
    for (int i = tid; i < COC * 64; i += 256) wt[i & 63][i >> 6] = cw[i];

    for (int it = 0; it < k; ++it) {
        u64 m = 0ULL;
        #pragma unroll
        for (int i = 0; i < 16; ++i) m = kreg[i] > m ? kreg[i] : m;
        #pragma unroll
        for (int off = 32; off > 0; off >>= 1) {
            u64 o = __shfl_xor(m, off, 64);
            m = o > m ? o : m;
        }
        if ((tid & 63) == 0) red[tid >> 6] = m;
        __syncthreads();
        u64 m0 = red[0], m1 = red[1], m2 = red[2], m3 = red[3];
        u64 ma = m0 > m1 ? m0 : m1;
        u64 mb = m2 > m3 ? m2 : m3;
        u64 mm = ma > mb ? ma : mb;
        if (tid == 0) sel[it] = (int)(~(u32)mm);
        #pragma unroll
        for (int i = 0; i < 16; ++i) if (kreg[i] == mm) kreg[i] = 0ULL;
        __syncthreads();
    }

    for (int t = tid; t < k * 32; t += 256) {
        const int r = t >> 5, i = t & 31;
        const size_t row = rowbase + sel[r];
        pooled[r][i]      = X[row * 32 + i];
        pooled[r][32 + i] = scale * fmaxf(acc[row * 32 + i], 0.0f);
    }
    __syncthreads();

    float* xo = xfeat + (size_t)g * MLP_IN + base;
    for (int t = tid; t < k * COC; t += 256) {
        const int r = t >> 4, co = t & 15;
        float s = 0.f;
        #pragma unroll
        for (int j = 0; j < 64; ++j) s = fmaf(pooled[r][j], wt[j][co], s);
        xo[co * k + r] = fmaxf(s, 0.f);
    }
}

// ---------------------------------------------------------------------------
// K4a: MLP stage 1 (k-split).  Block (g, s): partial_j = sum over 240 k's of
// x[k]*W1[k,j].  Coalesced W1 rows; x slice staged in LDS.  512 blocks.
// ---------------------------------------------------------------------------
__global__ __launch_bounds__(256) void mlp_stage1(
    const float* __restrict__ xfeat, const float* __restrict__ W1,
    float* __restrict__ hidp)
{
    const int g = blockIdx.x, s = blockIdx.y;
    const int tid = threadIdx.x;
    const int j = tid & 127, half = tid >> 7;

    __shared__ float xs[KCH];
    __shared__ float red[256];
    if (tid < KCH) xs[tid] = xfeat[(size_t)g * MLP_IN + s * KCH + tid];
    __syncthreads();

    const float* w = W1 + (size_t)(s * KCH + half * (KCH/2)) * MLP_H + j;
    const float* xh = xs + half * (KCH/2);
    float a = 0.f;
    #pragma unroll 4
    for (int i = 0; i < KCH/2; ++i)
        a = fmaf(xh[i], w[(size_t)i * MLP_H], a);

    red[tid] = a;
    __syncthreads();
    if (half == 0)
        hidp[((size_t)g * KSLICE + s) * MLP_H + j] = red[j] + red[128 + j];
}

// ---------------------------------------------------------------------------
// K4b: MLP stage 2: hid = relu(sum partials); out = hid @ W2   (f32 out)
// ---------------------------------------------------------------------------
__global__ __launch_bounds__(128) void mlp_stage2(
    const float* __restrict__ hidp, const float* __restrict__ W2,
    float* __restrict__ out)
{
    const int g = blockIdx.x, j = threadIdx.x;
    float h = 0.f;
    #pragma unroll
    for (int s = 0; s < KSLICE; ++s)
        h += hidp[((size_t)g * KSLICE + s) * MLP_H + j];
    h = fmaxf(h, 0.f);
    __shared__ float hid[MLP_H];
    hid[j] = h;
    __syncthreads();
    if (j < 2) {
        float o = 0.f;
        #pragma unroll 8
        for (int t = 0; t < MLP_H; ++t) o = fmaf(hid[t], W2[t * 2 + j], o);
        out[g * 2 + j] = o;
    }
}

// ---------------------------------------------------------------------------
extern "C" void kernel_launch(void* const* d_in, const int* in_sizes, int n_in,
                              void* d_out, int out_size, void* d_ws, size_t ws_size,
                              hipStream_t stream)
{
    const int*   L0r = (const int*)d_in[0];
    const int*   L0c = (const int*)d_in[1];
    const float* L0v = (const float*)d_in[2];
    const int*   L1r = (const int*)d_in[3];
    const int*   L1c = (const int*)d_in[4];
    const float* L1v = (const float*)d_in[5];
    const int*   L2r = (const int*)d_in[6];
    const int*   L2c = (const int*)d_in[7];
    const float* L2v = (const float*)d_in[8];
    const int*   D1r = (const int*)d_in[9];    // D1invB1    (N0 x N1)
    const int*   D1c = (const int*)d_in[10];
    const float* D1v = (const float*)d_in[11];
    const int*   D2r = (const int*)d_in[12];   // D2B1TD1inv (N1 x N0)
    const int*   D2c = (const int*)d_in[13];
    const float* D2v = (const float*)d_in[14];
    const int*   B2r = (const int*)d_in[15];   // B2TD2inv   (N2 x N1)
    const int*   B2c = (const int*)d_in[16];
    const float* B2v = (const float*)d_in[17];
    const int*   B3r = (const int*)d_in[18];   // B2D3       (N1 x N2)
    const int*   B3c = (const int*)d_in[19];
    const float* B3v = (const float*)d_in[20];
    const float* X0  = (const float*)d_in[21];
    const float* X1  = (const float*)d_in[22];
    const float* X2  = (const float*)d_in[23];
    const float* W_n2n = (const float*)d_in[24];
    const float* W_n2e = (const float*)d_in[25];
    const float* W_e2e = (const float*)d_in[26];
    const float* W_e2n = (const float*)d_in[27];
    const float* W_e2t = (const float*)d_in[28];
    const float* W_t2e = (const float*)d_in[29];
    const float* W_t2t = (const float*)d_in[30];
    const float* CWn = (const float*)d_in[31];
    const float* CWe = (const float*)d_in[32];
    const float* CWt = (const float*)d_in[33];
    const float* MW1 = (const float*)d_in[34];
    const float* MW2 = (const float*)d_in[35];

    const int nnzL0 = in_sizes[0],  nnzL1 = in_sizes[3],  nnzL2 = in_sizes[6];
    const int nnzD1 = in_sizes[9],  nnzD2 = in_sizes[12];
    const int nnzB2 = in_sizes[15], nnzB3 = in_sizes[18];

    int maxnnz = nnzL0;
    if (nnzL1 > maxnnz) maxnnz = nnzL1;
    if (nnzL2 > maxnnz) maxnnz = nnzL2;
    if (nnzD1 > maxnnz) maxnnz = nnzD1;
    if (nnzD2 > maxnnz) maxnnz = nnzD2;
    if (nnzB2 > maxnnz) maxnnz = nnzB2;
    if (nnzB3 > maxnnz) maxnnz = nnzB3;

    // --- workspace layout (16B-aligned sections) ---
    char* wp = (char*)d_ws;
    #define WALLOC(ty, name, count) \
        ty* name = (ty*)wp; wp += (((size_t)(count) * sizeof(ty)) + 15) & ~(size_t)15;
    WALLOC(float, Y,     (size_t)N1c * 32)
    WALLOC(float, acc0,  (size_t)N0c * 32)
    WALLOC(float, acc1,  (size_t)N1c * 32)
    WALLOC(float, acc2,  (size_t)N2c * 32)
    WALLOC(float, xfeat, (size_t)BG * MLP_IN)
    WALLOC(float, hidp,  (size_t)BG * KSLICE * MLP_H)
    WALLOC(u64,   pairs, (size_t)maxnnz)
    WALLOC(int,   ptr,   (size_t)N1c + 1)
    WALLOC(int,   bsum,  1024)
    const size_t need_B = (size_t)(wp - (char*)d_ws);
    WALLOC(u64,   tmpP,  (size_t)maxnnz)
    WALLOC(u32,   tmpR,  (size_t)maxnnz)
    WALLOC(int,   bincnt, 256)
    WALLOC(int,   binoff, 260)
    WALLOC(int,   gcur,   256)
    const size_t need_A = (size_t)(wp - (char*)d_ws);
    #undef WALLOC

    if (ws_size >= need_A) {
        // ============ tier A: binned two-pass CSR build, no row atomics ======
        #define BUILD_BIN(rp, cp, vp, nz, R)                                          \
            do {                                                                       \
                const int nbins = ((R) + BINROWS - 1) / BINROWS;                       \
                const int epb = nbins * 8;                                             \
                const int nblk = ((nz) + epb - 1) / epb;                               \
                hipMemsetAsync(bincnt, 0, (size_t)nbins * sizeof(int), stream);        \
                bin_hist<<<nblk, 256, 0, stream>>>((rp), (nz), epb, nbins, bincnt);    \
                bin_scan<<<1, 256, 0, stream>>>(bincnt, nbins, binoff, gcur);          \
                bin_scatter<<<nblk, 256, 0, stream>>>((rp), (cp), (vp), (nz), epb,     \
                                                      nbins, gcur, tmpP, tmpR);        \
                bin_build<<<nbins, 256, 0, stream>>>(binoff, tmpP, tmpR, (R),          \
                                                     pairs, ptr);                      \
            } while (0)
        #define LIFT(Xp, Np, Wp) \
            gemm_lift<<<((Np) + 255) / 256, 256, 0, stream>>>((Xp), (Np), (Wp), Y)
        #define SPMM_CSR(R, accp, store) \
            spmm_csr<<<(((R) * 8) + 255) / 256, 256, 0, stream>>>(ptr, pairs, Y, (accp), (R), (store))

        BUILD_BIN(L0r, L0c, L0v, nnzL0, N0c); LIFT(X0, N0c, W_n2n); SPMM_CSR(N0c, acc0, 1); // n2n
        BUILD_BIN(D2r, D2c, D2v, nnzD2, N1c); LIFT(X0, N0c, W_n2e); SPMM_CSR(N1c, acc1, 1); // n2e
        BUILD_BIN(L1r, L1c, L1v, nnzL1, N1c); LIFT(X1, N1c, W_e2e); SPMM_CSR(N1c, acc1, 0); // e2e
        BUILD_BIN(D1r, D1c, D1v, nnzD1, N0c); LIFT(X1, N1c, W_e2n); SPMM_CSR(N0c, acc0, 0); // e2n
        BUILD_BIN(B2r, B2c, B2v, nnzB2, N2c); LIFT(X1, N1c, W_e2t); SPMM_CSR(N2c, acc2, 1); // e2t
        BUILD_BIN(L2r, L2c, L2v, nnzL2, N2c); LIFT(X2, N2c, W_t2t); SPMM_CSR(N2c, acc2, 0); // t2t
        BUILD_BIN(B3r, B3c, B3v, nnzB3, N1c); LIFT(X2, N2c, W_t2e); SPMM_CSR(N1c, acc1, 0); // t2e

        #undef BUILD_BIN
        #undef LIFT
        #undef SPMM_CSR
    } else if (ws_size >= need_B) {
        // ============ tier B: CSR path (atomic scatter) ======================
        #define BUILD_CSR(rp, cp, vp, nz, R)                                         \
            do {                                                                      \
                hipMemsetAsync(ptr, 0, ((size_t)(R) + 1) * sizeof(int), stream);      \
                hist_kernel<<<((nz) + 255) / 256, 256, 0, stream>>>((rp), (nz), ptr); \
                const int nb = ((R) + 1023) / 1024;                                   \
                scan_reduce<<<nb, 256, 0, stream>>>(ptr, (R), bsum);                  \
                scan_partials<<<1, 1024, 0, stream>>>(bsum, nb);                      \
                scan_write<<<nb, 256, 0, stream>>>(ptr, (R), bsum);                   \
                scatter_kernel<<<((nz) + 255) / 256, 256, 0, stream>>>(               \
                    (rp), (cp), (vp), (nz), ptr, pairs);                              \
            } while (0)
        #define LIFT(Xp, Np, Wp) \
            gemm_lift<<<((Np) + 255) / 256, 256, 0, stream>>>((Xp), (Np), (Wp), Y)
        #define SPMM_CSR(R, accp, store) \
            spmm_csr<<<(((R) * 8) + 255) / 256, 256, 0, stream>>>(ptr, pairs, Y, (accp), (R), (store))

        BUILD_CSR(L0r, L0c, L0v, nnzL0, N0c); LIFT(X0, N0c, W_n2n); SPMM_CSR(N0c, acc0, 1);
        BUILD_CSR(D2r, D2c, D2v, nnzD2, N1c); LIFT(X0, N0c, W_n2e); SPMM_CSR(N1c, acc1, 1);
        BUILD_CSR(L1r, L1c, L1v, nnzL1, N1c); LIFT(X1, N1c, W_e2e); SPMM_CSR(N1c, acc1, 0);
        BUILD_CSR(D1r, D1c, D1v, nnzD1, N0c); LIFT(X1, N1c, W_e2n); SPMM_CSR(N0c, acc0, 0);
        BUILD_CSR(B2r, B2c, B2v, nnzB2, N2c); LIFT(X1, N1c, W_e2t); SPMM_CSR(N2c, acc2, 1);
        BUILD_CSR(L2r, L2c, L2v, nnzL2, N2c); LIFT(X2, N2c, W_t2t); SPMM_CSR(N2c, acc2, 0);
        BUILD_CSR(B3r, B3c, B3v, nnzB3, N1c); LIFT(X2, N2c, W_t2e); SPMM_CSR(N1c, acc1, 0);

        #undef BUILD_CSR
        #undef LIFT
        #undef SPMM_CSR
    } else {
        // ============ tier C: atomic COO path ================================
        hipMemsetAsync(acc0, 0, (size_t)(N0c + N1c + N2c) * 32 * sizeof(float), stream);
        #define LIFT(Xp, Np, Wp) \
            gemm_lift<<<((Np) + 255) / 256, 256, 0, stream>>>((Xp), (Np), (Wp), Y)
        #define SPMM(rp, cp, vp, nz, accp) \
            spmm_kernel<<<((nz) * 8 + 255) / 256, 256, 0, stream>>>((rp), (cp), (vp), Y, (accp), (nz))
        LIFT(X0, N0c, W_n2n);  SPMM(L0r, L0c, L0v, nnzL0, acc0);
        LIFT(X0, N0c, W_n2e);  SPMM(D2r, D2c, D2v, nnzD2, acc1);
        LIFT(X1, N1c, W_e2e);  SPMM(L1r, L1c, L1v, nnzL1, acc1);
        LIFT(X1, N1c, W_e2n);  SPMM(D1r, D1c, D1v, nnzD1, acc0);
        LIFT(X1, N1c, W_e2t);  SPMM(B2r, B2c, B2v, nnzB2, acc2);
        LIFT(X2, N2c, W_t2t);  SPMM(L2r, L2c, L2v, nnzL2, acc2);
        LIFT(X2, N2c, W_t2e);  SPMM(B3r, B3c, B3v, nnzB3, acc1);
        #undef LIFT
        #undef SPMM
    }

    topk_conv_kernel<<<dim3(BG, 3), 256, 0, stream>>>(X0, X1, X2, acc0, acc1, acc2,
                                                      CWn, CWe, CWt, xfeat);
    mlp_stage1<<<dim3(BG, KSLICE), 256, 0, stream>>>(xfeat, MW1, hidp);
    mlp_stage2<<<BG, MLP_H, 0, stream>>>(hidp, MW2, (float*)d_out);
}

// Round 7
// 932.215 us; speedup vs baseline: 2.8982x; 1.0059x over previous
//
#include <hip/hip_runtime.h>

// ---------------- problem constants (fixed by reference) ----------------
#define N0c 128000
#define N1c 256000
#define N2c 128000
#define BG  64        // graphs per batch
#define KNc 30
#define KEc 60
#define KTc 30
#define COC 16        // conv out channels
#define MLP_IN 1920   // 16*(30+60+30)
#define MLP_H 128
#define KSLICE 8      // MLP stage-1 k-split
#define KCH (MLP_IN / KSLICE)   // 240

#define BINSHIFT 10           // 1024 rows per bin
#define BINROWS  1024
#define BDEPTH   16           // LDS staging depth per bin (pass 1)
#define BCAP     12288        // max entries per bin in pass 2 (mean ~8192)

typedef unsigned long long u64;
typedef unsigned int u32;

// ---------------------------------------------------------------------------
// K1: fused polynomial lift + dense GEMM.  Y[row] = [x, x*x] @ W   (64 -> 32)
// ---------------------------------------------------------------------------
__global__ __launch_bounds__(256) void gemm_lift(
    const float* __restrict__ X, int N, const float* __restrict__ W,
    float* __restrict__ Y)
{
    __shared__ float lw[2048];            // [64][32]
    const int tid = threadIdx.x;
    for (int i = tid; i < 2048; i += 256) lw[i] = W[i];
    __syncthreads();

    const int row = blockIdx.x * 256 + tid;
    if (row >= N) return;

    float x[64];
    const float4* p = reinterpret_cast<const float4*>(X + (size_t)row * 32);
    #pragma unroll
    for (int q = 0; q < 8; ++q) {
        float4 v = p[q];
        x[q*4+0] = v.x; x[q*4+1] = v.y; x[q*4+2] = v.z; x[q*4+3] = v.w;
    }
    #pragma unroll
    for (int i = 0; i < 32; ++i) x[32+i] = x[i] * x[i];

    const float4* lw4 = reinterpret_cast<const float4*>(lw);
    float4* yo = reinterpret_cast<float4*>(Y + (size_t)row * 32);
    #pragma unroll
    for (int j4 = 0; j4 < 8; ++j4) {
        float4 s = {0.f, 0.f, 0.f, 0.f};
        #pragma unroll
        for (int i = 0; i < 64; ++i) {
            float4 wf = lw4[i * 8 + j4];     // broadcast LDS read
            s.x = fmaf(x[i], wf.x, s.x);
            s.y = fmaf(x[i], wf.y, s.y);
            s.z = fmaf(x[i], wf.z, s.z);
            s.w = fmaf(x[i], wf.w, s.w);
        }
        yo[j4] = s;
    }
}

// ====================== binned CSR build (tier A) ===========================
__global__ __launch_bounds__(256) void bin_hist(
    const int* __restrict__ rows, int nnz, int epb, int nbins,
    int* __restrict__ bincnt)
{
    __shared__ int lh[256];
    const int tid = threadIdx.x;
    lh[tid] = 0;
    __syncthreads();
    const int base = blockIdx.x * epb;
    const int cnt = min(epb, nnz - base);
    for (int i = tid; i < cnt; i += 256)
        atomicAdd(&lh[rows[base + i] >> BINSHIFT], 1);
    __syncthreads();
    if (tid < nbins && lh[tid]) atomicAdd(&bincnt[tid], lh[tid]);
}

__global__ __launch_bounds__(256) void bin_scan(
    const int* __restrict__ bincnt, int nbins,
    int* __restrict__ binoff, int* __restrict__ gcur)
{
    __shared__ int sm[256];
    const int tid = threadIdx.x;
    const int v = (tid < nbins) ? bincnt[tid] : 0;
    sm[tid] = v;
    __syncthreads();
    for (int off = 1; off < 256; off <<= 1) {
        int t = (tid >= off) ? sm[tid - off] : 0;
        __syncthreads();
        sm[tid] += t;
        __syncthreads();
    }
    const int ex = sm[tid] - v;            // exclusive
    if (tid < nbins) { binoff[tid] = ex; gcur[tid] = ex; }
    if (tid == 255) binoff[nbins] = sm[255];
}

__global__ __launch_bounds__(256) void bin_scatter(
    const int* __restrict__ rows, const int* __restrict__ cols,
    const float* __restrict__ vals, int nnz, int epb, int nbins,
    int* __restrict__ gcur, u64* __restrict__ tmpP, u32* __restrict__ tmpR)
{
    __shared__ u64 bP[256 * BDEPTH];   // 32 KB
    __shared__ u32 bR[256 * BDEPTH];   // 16 KB
    __shared__ int lc[256];
    const int tid = threadIdx.x;
    lc[tid] = 0;
    __syncthreads();
    const int base = blockIdx.x * epb;
    const int cnt = min(epb, nnz - base);
    for (int i = tid; i < cnt; i += 256) {
        const int e = base + i;
        const int r = rows[e];
        const u64 pv = ((u64)__float_as_uint(vals[e]) << 32) | (u32)cols[e];
        const int b = r >> BINSHIFT;
        const int p = atomicAdd(&lc[b], 1);
        if (p < BDEPTH) {
            bP[b * BDEPTH + p] = pv;
            bR[b * BDEPTH + p] = (u32)r;
        } else {                               // rare spill (~1%)
            const int g = atomicAdd(&gcur[b], 1);
            tmpP[g] = pv; tmpR[g] = (u32)r;
        }
    }
    __syncthreads();
    if (tid < nbins) {
        int len = lc[tid]; if (len > BDEPTH) len = BDEPTH;
        if (len) {
            const int g = atomicAdd(&gcur[tid], len);
            for (int i = 0; i < len; ++i) {
                tmpP[g + i] = bP[tid * BDEPTH + i];
                tmpR[g + i] = bR[tid * BDEPTH + i];
            }
        }
    }
}

__global__ __launch_bounds__(256) void bin_build(
    const int* __restrict__ binoff, const u64* __restrict__ tmpP,
    const u32* __restrict__ tmpR, int R,
    u64* __restrict__ pairs, int* __restrict__ ptr)
{
    __shared__ unsigned short rl[BCAP];        // 24 KB
    __shared__ int h[BINROWS];                 // 4 KB
    __shared__ int cur[BINROWS];               // 4 KB
    __shared__ int sm[256];
    const int b = blockIdx.x, tid = threadIdx.x;
    const int base = binoff[b];
    int len = binoff[b + 1] - base;
    if (len > BCAP) len = BCAP;                // never expected

    for (int i = tid; i < BINROWS; i += 256) h[i] = 0;
    __syncthreads();
    for (int i = tid; i < len; i += 256) {
        const int r = (int)(tmpR[base + i] & (BINROWS - 1));
        rl[i] = (unsigned short)r;
        atomicAdd(&h[r], 1);
    }
    __syncthreads();

    const int i0 = tid * 4;
    const int a0 = h[i0], a1 = h[i0+1], a2 = h[i0+2], a3 = h[i0+3];
    const int s = a0 + a1 + a2 + a3;
    sm[tid] = s;
    __syncthreads();
    for (int off = 1; off < 256; off <<= 1) {
        int t = (tid >= off) ? sm[tid - off] : 0;
        __syncthreads();
        sm[tid] += t;
        __syncthreads();
    }
    const int run = sm[tid] - s;
    cur[i0]   = run;
    cur[i0+1] = run + a0;
    cur[i0+2] = run + a0 + a1;
    cur[i0+3] = run + a0 + a1 + a2;
    const int rstart = b << BINSHIFT;
    if (rstart + i0     < R) ptr[rstart + i0    ] = base + run + a0;
    if (rstart + i0 + 1 < R) ptr[rstart + i0 + 1] = base + run + a0 + a1;
    if (rstart + i0 + 2 < R) ptr[rstart + i0 + 2] = base + run + a0 + a1 + a2;
    if (rstart + i0 + 3 < R) ptr[rstart + i0 + 3] = base + run + a0 + a1 + a2 + a3;
    __syncthreads();

    for (int i = tid; i < len; i += 256) {
        const int r = rl[i];
        const int pos = base + atomicAdd(&cur[r], 1);
        pairs[pos] = tmpP[base + i];
    }
}

// ================== legacy CSR build kernels (tier B fallback) ==============
__global__ __launch_bounds__(256) void hist_kernel(
    const int* __restrict__ rows, int nnz, int* __restrict__ ptr)
{
    const int e = blockIdx.x * 256 + threadIdx.x;
    if (e < nnz) atomicAdd(&ptr[rows[e]], 1);
}

__global__ __launch_bounds__(256) void scan_reduce(
    const int* __restrict__ cnt, int n, int* __restrict__ bsum)
{
    __shared__ int sm[256];
    const int b = blockIdx.x, tid = threadIdx.x;
    const int base = b * 1024 + tid * 4;
    int s = 0;
    if (base + 3 < n) {
        int4 v = *reinterpret_cast<const int4*>(cnt + base);
        s = v.x + v.y + v.z + v.w;
    } else {
        for (int i = 0; i < 4; ++i) if (base + i < n) s += cnt[base + i];
    }
    sm[tid] = s; __syncthreads();
    #pragma unroll
    for (int st = 128; st > 0; st >>= 1) {
        if (tid < st) sm[tid] += sm[tid + st];
        __syncthreads();
    }
    if (tid == 0) bsum[b] = sm[0];
}

__global__ __launch_bounds__(1024) void scan_partials(int* __restrict__ bsum, int nb)
{
    __shared__ int sm[1024];
    const int tid = threadIdx.x;
    sm[tid] = (tid < nb) ? bsum[tid] : 0;
    __syncthreads();
    for (int off = 1; off < 1024; off <<= 1) {
        int v = (tid >= off) ? sm[tid - off] : 0;
        __syncthreads();
        sm[tid] += v;
        __syncthreads();
    }
    if (tid < nb) bsum[tid] = (tid == 0) ? 0 : sm[tid - 1];
}

__global__ __launch_bounds__(256) void scan_write(
    int* __restrict__ ptr, int n, const int* __restrict__ bsum)
{
    __shared__ int sm[256];
    const int b = blockIdx.x, tid = threadIdx.x;
    const int base = b * 1024 + tid * 4;
    int v[4]; int s = 0;
    #pragma unroll
    for (int i = 0; i < 4; ++i) {
        v[i] = (base + i < n) ? ptr[base + i] : 0;
        s += v[i];
    }
    sm[tid] = s; __syncthreads();
    for (int off = 1; off < 256; off <<= 1) {
        int t = (tid >= off) ? sm[tid - off] : 0;
        __syncthreads();
        sm[tid] += t;
        __syncthreads();
    }
    int run = bsum[b] + sm[tid] - s;
    #pragma unroll
    for (int i = 0; i < 4; ++i) {
        if (base + i < n) ptr[base + i] = run;
        run += v[i];
    }
}

__global__ __launch_bounds__(256) void scatter_kernel(
    const int* __restrict__ rows, const int* __restrict__ cols,
    const float* __restrict__ vals, int nnz,
    int* __restrict__ ptr, u64* __restrict__ pairs)
{
    const int e = blockIdx.x * 256 + threadIdx.x;
    if (e >= nnz) return;
    const int pos = atomicAdd(&ptr[rows[e]], 1);
    pairs[pos] = ((u64)__float_as_uint(vals[e]) << 32) | (u32)cols[e];
}

// ---------------------------------------------------------------------------
// K2': CSR gather SPMM.  8 lanes per row; lane j owns float4 chunk j.
// If keyout != null (final accumulate for this level), lane 7 also emits
// key[row] = kscale * relu(final col 31) -- fuses sortpool key extraction.
// ---------------------------------------------------------------------------
__global__ __launch_bounds__(256) void spmm_csr(
    const int* __restrict__ ptr, const u64* __restrict__ pairs,
    const float* __restrict__ Y, float* __restrict__ acc, int R, int STORE,
    float* __restrict__ keyout, float kscale)
{
    const int t = blockIdx.x * 256 + threadIdx.x;
    const int row = t >> 3;
    const int l8  = t & 7;
    if (row >= R) return;
    const int s = (row == 0) ? 0 : ptr[row - 1];
    const int e = ptr[row];

    const float4* Y4 = reinterpret_cast<const float4*>(Y);
    float4 a = {0.f, 0.f, 0.f, 0.f};
    for (int base = s; base < e; base += 8) {
        int m = e - base; if (m > 8) m = 8;
        u64 pk = (l8 < m) ? pairs[base + l8] : 0ULL;
        for (int j = 0; j < m; ++j) {
            const u64 pj = __shfl(pk, j, 8);
            const int col   = (int)(u32)(pj & 0xffffffffu);
            const float val = __uint_as_float((u32)(pj >> 32));
            const float4 y = Y4[(size_t)col * 8 + l8];
            a.x = fmaf(val, y.x, a.x); a.y = fmaf(val, y.y, a.y);
            a.z = fmaf(val, y.z, a.z); a.w = fmaf(val, y.w, a.w);
        }
    }
    float4* ap = reinterpret_cast<float4*>(acc) + (size_t)row * 8 + l8;
    float fin;
    if (STORE) {
        *ap = a;
        fin = a.w;
    } else {
        float4 o = *ap;
        o.x += a.x; o.y += a.y; o.z += a.z; o.w += a.w;
        *ap = o;
        fin = o.w;
    }
    if (keyout && l8 == 7)
        keyout[row] = kscale * fmaxf(fin, 0.0f);
}

// ---------------------------------------------------------------------------
// K2 (tier C fallback): atomic COO SPMM
// ---------------------------------------------------------------------------
__global__ __launch_bounds__(256) void spmm_kernel(
    const int* __restrict__ rows, const int* __restrict__ cols,
    const float* __restrict__ vals,
    const float* __restrict__ Y, float* __restrict__ acc, int nnz)
{
    const int t = blockIdx.x * 256 + threadIdx.x;
    const int e = t >> 3, c = t & 7;
    if (e >= nnz) return;
    const int r = rows[e], col = cols[e];
    const float v = vals[e];
    const float4 yv = reinterpret_cast<const float4*>(Y + (size_t)col * 32)[c];
    float* a = acc + (size_t)r * 32 + c * 4;
    unsafeAtomicAdd(a + 0, v * yv.x);
    unsafeAtomicAdd(a + 1, v * yv.y);
    unsafeAtomicAdd(a + 2, v * yv.z);
    unsafeAtomicAdd(a + 3, v * yv.w);
}

// ---------------------------------------------------------------------------
// K3: per (graph, level) top-k + pooled gather + conv1d(kernel=stride=64)+relu
// Keys come from the compact per-level key array (coalesced); falls back to
// strided acc column read if keys == nullptr (tier C).
// ---------------------------------------------------------------------------
__global__ __launch_bounds__(256) void topk_conv_kernel(
    const float* __restrict__ X0, const float* __restrict__ X1,
    const float* __restrict__ X2,
    const float* __restrict__ acc0, const float* __restrict__ acc1,
    const float* __restrict__ acc2,
    const float* __restrict__ keys0, const float* __restrict__ keys1,
    const float* __restrict__ keys2,
    const float* __restrict__ CW0, const float* __restrict__ CW1,
    const float* __restrict__ CW2,
    float* __restrict__ xfeat)
{
    const int lvl = blockIdx.y;
    const int g   = blockIdx.x;
    int n, k, base; const float* X; const float* acc; const float* keys;
    const float* cw; float scale;
    if (lvl == 0)      { n = 2000; k = KNc; base = 0;             X = X0; acc = acc0; keys = keys0; cw = CW0; scale = 0.5f; }
    else if (lvl == 1) { n = 4000; k = KEc; base = COC*KNc;       X = X1; acc = acc1; keys = keys1; cw = CW1; scale = 1.0f/3.0f; }
    else               { n = 2000; k = KTc; base = COC*(KNc+KEc); X = X2; acc = acc2; keys = keys2; cw = CW2; scale = 0.5f; }

    __shared__ u64 red[4];
    __shared__ float pooled[KEc][68];
    __shared__ float wt[64][16];
    __shared__ int   sel[KEc];

    const int tid = threadIdx.x;
    const size_t rowbase = (size_t)g * n;

    u64 kreg[16];
    #pragma unroll
    for (int i = 0; i < 16; ++i) {
        const int r = i * 256 + tid;
        u64 kk = 0ULL;
        if (r < n) {
            const float kv = keys ? keys[rowbase + r]
                                  : scale * fmaxf(acc[(rowbase + r) * 32 + 31], 0.0f);
            const u32 kb = (kv > 0.0f) ? __float_as_uint(kv) : 0u;  // kill -0.0
            kk = ((u64)kb << 32) | (u32)(~r);
        }
        kreg[i] = kk;
    }
    for (int i = tid; i < COC * 64; i += 256) wt[i & 63][i >> 6] = cw[i];

    for (int it = 0; it < k; ++it) {
        u64 m = 0ULL;
        #pragma unroll
        for (int i = 0; i < 16; ++i) m = kreg[i] > m ? kreg[i] : m;
        #pragma unroll
        for (int off = 32; off > 0; off >>= 1) {
            u64 o = __shfl_xor(m, off, 64);
            m = o > m ? o : m;
        }
        if ((tid & 63) == 0) red[tid >> 6] = m;
        __syncthreads();
        u64 m0 = red[0], m1 = red[1], m2 = red[2], m3 = red[3];
        u64 ma = m0 > m1 ? m0 : m1;
        u64 mb = m2 > m3 ? m2 : m3;
        u64 mm = ma > mb ? ma : mb;
        if (tid == 0) sel[it] = (int)(~(u32)mm);
        #pragma unroll
        for (int i = 0; i < 16; ++i) if (kreg[i] == mm) kreg[i] = 0ULL;
        __syncthreads();
    }

    for (int t = tid; t < k * 32; t += 256) {
        const int r = t >> 5, i = t & 31;
        const size_t row = rowbase + sel[r];
        pooled[r][i]      = X[row * 32 + i];
        pooled[r][32 + i] = scale * fmaxf(acc[row * 32 + i], 0.0f);
    }
    __syncthreads();

    float* xo = xfeat + (size_t)g * MLP_IN + base;
    for (int t = tid; t < k * COC; t += 256) {
        const int r = t >> 4, co = t & 15;
        float s = 0.f;
        #pragma unroll
        for (int j = 0; j < 64; ++j) s = fmaf(pooled[r][j], wt[j][co], s);
        xo[co * k + r] = fmaxf(s, 0.f);
    }
}

// ---------------------------------------------------------------------------
// K4a: MLP stage 1 (k-split).  Block (g, s): partial over 240 k's.
// ---------------------------------------------------------------------------
__global__ __launch_bounds__(256) void mlp_stage1(
    const float* __restrict__ xfeat, const float* __restrict__ W1,
    float* __restrict__ hidp)
{
    const int g = blockIdx.x, s = blockIdx.y;
    const int tid = threadIdx.x;
    const int j = tid & 127, half = tid >> 7;

    __shared__ float xs[KCH];
    __shared__ float red[256];
    if (tid < KCH) xs[tid] = xfeat[(size_t)g * MLP_IN + s * KCH + tid];
    __syncthreads();

    const float* w = W1 + (size_t)(s * KCH + half * (KCH/2)) * MLP_H + j;
    const float* xh = xs + half * (KCH/2);
    float a = 0.f;
    #pragma unroll 4
    for (int i = 0; i < KCH/2; ++i)
        a = fmaf(xh[i], w[(size_t)i * MLP_H], a);

    red[tid] = a;
    __syncthreads();
    if (half == 0)
        hidp[((size_t)g * KSLICE + s) * MLP_H + j] = red[j] + red[128 + j];
}

// ---------------------------------------------------------------------------
// K4b: MLP stage 2: hid = relu(sum partials); out = hid @ W2   (f32 out)
// ---------------------------------------------------------------------------
__global__ __launch_bounds__(128) void mlp_stage2(
    const float* __restrict__ hidp, const float* __restrict__ W2,
    float* __restrict__ out)
{
    const int g = blockIdx.x, j = threadIdx.x;
    float h = 0.f;
    #pragma unroll
    for (int s = 0; s < KSLICE; ++s)
        h += hidp[((size_t)g * KSLICE + s) * MLP_H + j];
    h = fmaxf(h, 0.f);
    __shared__ float hid[MLP_H];
    hid[j] = h;
    __syncthreads();
    if (j < 2) {
        float o = 0.f;
        #pragma unroll 8
        for (int t = 0; t < MLP_H; ++t) o = fmaf(hid[t], W2[t * 2 + j], o);
        out[g * 2 + j] = o;
    }
}

// ---------------------------------------------------------------------------
extern "C" void kernel_launch(void* const* d_in, const int* in_sizes, int n_in,
                              void* d_out, int out_size, void* d_ws, size_t ws_size,
                              hipStream_t stream)
{
    const int*   L0r = (const int*)d_in[0];
    const int*   L0c = (const int*)d_in[1];
    const float* L0v = (const float*)d_in[2];
    const int*   L1r = (const int*)d_in[3];
    const int*   L1c = (const int*)d_in[4];
    const float* L1v = (const float*)d_in[5];
    const int*   L2r = (const int*)d_in[6];
    const int*   L2c = (const int*)d_in[7];
    const float* L2v = (const float*)d_in[8];
    const int*   D1r = (const int*)d_in[9];    // D1invB1    (N0 x N1)
    const int*   D1c = (const int*)d_in[10];
    const float* D1v = (const float*)d_in[11];
    const int*   D2r = (const int*)d_in[12];   // D2B1TD1inv (N1 x N0)
    const int*   D2c = (const int*)d_in[13];
    const float* D2v = (const float*)d_in[14];
    const int*   B2r = (const int*)d_in[15];   // B2TD2inv   (N2 x N1)
    const int*   B2c = (const int*)d_in[16];
    const float* B2v = (const float*)d_in[17];
    const int*   B3r = (const int*)d_in[18];   // B2D3       (N1 x N2)
    const int*   B3c = (const int*)d_in[19];
    const float* B3v = (const float*)d_in[20];
    const float* X0  = (const float*)d_in[21];
    const float* X1  = (const float*)d_in[22];
    const float* X2  = (const float*)d_in[23];
    const float* W_n2n = (const float*)d_in[24];
    const float* W_n2e = (const float*)d_in[25];
    const float* W_e2e = (const float*)d_in[26];
    const float* W_e2n = (const float*)d_in[27];
    const float* W_e2t = (const float*)d_in[28];
    const float* W_t2e = (const float*)d_in[29];
    const float* W_t2t = (const float*)d_in[30];
    const float* CWn = (const float*)d_in[31];
    const float* CWe = (const float*)d_in[32];
    const float* CWt = (const float*)d_in[33];
    const float* MW1 = (const float*)d_in[34];
    const float* MW2 = (const float*)d_in[35];

    const int nnzL0 = in_sizes[0],  nnzL1 = in_sizes[3],  nnzL2 = in_sizes[6];
    const int nnzD1 = in_sizes[9],  nnzD2 = in_sizes[12];
    const int nnzB2 = in_sizes[15], nnzB3 = in_sizes[18];

    int maxnnz = nnzL0;
    if (nnzL1 > maxnnz) maxnnz = nnzL1;
    if (nnzL2 > maxnnz) maxnnz = nnzL2;
    if (nnzD1 > maxnnz) maxnnz = nnzD1;
    if (nnzD2 > maxnnz) maxnnz = nnzD2;
    if (nnzB2 > maxnnz) maxnnz = nnzB2;
    if (nnzB3 > maxnnz) maxnnz = nnzB3;

    // --- workspace layout (16B-aligned sections) ---
    char* wp = (char*)d_ws;
    #define WALLOC(ty, name, count) \
        ty* name = (ty*)wp; wp += (((size_t)(count) * sizeof(ty)) + 15) & ~(size_t)15;
    WALLOC(float, Y,     (size_t)N1c * 32)
    WALLOC(float, acc0,  (size_t)N0c * 32)
    WALLOC(float, acc1,  (size_t)N1c * 32)
    WALLOC(float, acc2,  (size_t)N2c * 32)
    WALLOC(float, xfeat, (size_t)BG * MLP_IN)
    WALLOC(float, hidp,  (size_t)BG * KSLICE * MLP_H)
    WALLOC(float, keys0, (size_t)N0c)
    WALLOC(float, keys1, (size_t)N1c)
    WALLOC(float, keys2, (size_t)N2c)
    WALLOC(u64,   pairs, (size_t)maxnnz)
    WALLOC(int,   ptr,   (size_t)N1c + 1)
    WALLOC(int,   bsum,  1024)
    const size_t need_B = (size_t)(wp - (char*)d_ws);
    WALLOC(u64,   tmpP,  (size_t)maxnnz)
    WALLOC(u32,   tmpR,  (size_t)maxnnz)
    WALLOC(int,   bincnt, 256)
    WALLOC(int,   binoff, 260)
    WALLOC(int,   gcur,   256)
    const size_t need_A = (size_t)(wp - (char*)d_ws);
    #undef WALLOC

    const float* tk_keys0 = keys0;
    const float* tk_keys1 = keys1;
    const float* tk_keys2 = keys2;

    if (ws_size >= need_A) {
        // ============ tier A: binned two-pass CSR build, no row atomics ======
        #define BUILD_BIN(rp, cp, vp, nz, R)                                          \
            do {                                                                       \
                const int nbins = ((R) + BINROWS - 1) / BINROWS;                       \
                const int epb = nbins * 8;                                             \
                const int nblk = ((nz) + epb - 1) / epb;                               \
                hipMemsetAsync(bincnt, 0, (size_t)nbins * sizeof(int), stream);        \
                bin_hist<<<nblk, 256, 0, stream>>>((rp), (nz), epb, nbins, bincnt);    \
                bin_scan<<<1, 256, 0, stream>>>(bincnt, nbins, binoff, gcur);          \
                bin_scatter<<<nblk, 256, 0, stream>>>((rp), (cp), (vp), (nz), epb,     \
                                                      nbins, gcur, tmpP, tmpR);        \
                bin_build<<<nbins, 256, 0, stream>>>(binoff, tmpP, tmpR, (R),          \
                                                     pairs, ptr);                      \
            } while (0)
        #define LIFT(Xp, Np, Wp) \
            gemm_lift<<<((Np) + 255) / 256, 256, 0, stream>>>((Xp), (Np), (Wp), Y)
        #define SPMM_CSR(R, accp, store, keyp, ks) \
            spmm_csr<<<(((R) * 8) + 255) / 256, 256, 0, stream>>>(ptr, pairs, Y, (accp), (R), (store), (keyp), (ks))

        BUILD_BIN(L0r, L0c, L0v, nnzL0, N0c); LIFT(X0, N0c, W_n2n); SPMM_CSR(N0c, acc0, 1, (float*)0, 0.f);      // n2n
        BUILD_BIN(D2r, D2c, D2v, nnzD2, N1c); LIFT(X0, N0c, W_n2e); SPMM_CSR(N1c, acc1, 1, (float*)0, 0.f);      // n2e
        BUILD_BIN(L1r, L1c, L1v, nnzL1, N1c); LIFT(X1, N1c, W_e2e); SPMM_CSR(N1c, acc1, 0, (float*)0, 0.f);      // e2e
        BUILD_BIN(D1r, D1c, D1v, nnzD1, N0c); LIFT(X1, N1c, W_e2n); SPMM_CSR(N0c, acc0, 0, keys0, 0.5f);         // e2n (final acc0)
        BUILD_BIN(B2r, B2c, B2v, nnzB2, N2c); LIFT(X1, N1c, W_e2t); SPMM_CSR(N2c, acc2, 1, (float*)0, 0.f);      // e2t
        BUILD_BIN(L2r, L2c, L2v, nnzL2, N2c); LIFT(X2, N2c, W_t2t); SPMM_CSR(N2c, acc2, 0, keys2, 0.5f);         // t2t (final acc2)
        BUILD_BIN(B3r, B3c, B3v, nnzB3, N1c); LIFT(X2, N2c, W_t2e); SPMM_CSR(N1c, acc1, 0, keys1, 1.0f/3.0f);    // t2e (final acc1)

        #undef BUILD_BIN
        #undef LIFT
        #undef SPMM_CSR
    } else if (ws_size >= need_B) {
        // ============ tier B: CSR path (atomic scatter) ======================
        #define BUILD_CSR(rp, cp, vp, nz, R)                                         \
            do {                                                                      \
                hipMemsetAsync(ptr, 0, ((size_t)(R) + 1) * sizeof(int), stream);      \
                hist_kernel<<<((nz) + 255) / 256, 256, 0, stream>>>((rp), (nz), ptr); \
                const int nb = ((R) + 1023) / 1024;                                   \
                scan_reduce<<<nb, 256, 0, stream>>>(ptr, (R), bsum);                  \
                scan_partials<<<1, 1024, 0, stream>>>(bsum, nb);                      \
                scan_write<<<nb, 256, 0, stream>>>(ptr, (R), bsum);                   \
                scatter_kernel<<<((nz) + 255) / 256, 256, 0, stream>>>(               \
                    (rp), (cp), (vp), (nz), ptr, pairs);                              \
            } while (0)
        #define LIFT(Xp, Np, Wp) \
            gemm_lift<<<((Np) + 255) / 256, 256, 0, stream>>>((Xp), (Np), (Wp), Y)
        #define SPMM_CSR(R, accp, store, keyp, ks) \
            spmm_csr<<<(((R) * 8) + 255) / 256, 256, 0, stream>>>(ptr, pairs, Y, (accp), (R), (store), (keyp), (ks))

        BUILD_CSR(L0r, L0c, L0v, nnzL0, N0c); LIFT(X0, N0c, W_n2n); SPMM_CSR(N0c, acc0, 1, (float*)0, 0.f);
        BUILD_CSR(D2r, D2c, D2v, nnzD2, N1c); LIFT(X0, N0c, W_n2e); SPMM_CSR(N1c, acc1, 1, (float*)0, 0.f);
        BUILD_CSR(L1r, L1c, L1v, nnzL1, N1c); LIFT(X1, N1c, W_e2e); SPMM_CSR(N1c, acc1, 0, (float*)0, 0.f);
        BUILD_CSR(D1r, D1c, D1v, nnzD1, N0c); LIFT(X1, N1c, W_e2n); SPMM_CSR(N0c, acc0, 0, keys0, 0.5f);
        BUILD_CSR(B2r, B2c, B2v, nnzB2, N2c); LIFT(X1, N1c, W_e2t); SPMM_CSR(N2c, acc2, 1, (float*)0, 0.f);
        BUILD_CSR(L2r, L2c, L2v, nnzL2, N2c); LIFT(X2, N2c, W_t2t); SPMM_CSR(N2c, acc2, 0, keys2, 0.5f);
        BUILD_CSR(B3r, B3c, B3v, nnzB3, N1c); LIFT(X2, N2c, W_t2e); SPMM_CSR(N1c, acc1, 0, keys1, 1.0f/3.0f);

        #undef BUILD_CSR
        #undef LIFT
        #undef SPMM_CSR
    } else {
        // ============ tier C: atomic COO path (keys unavailable) =============
        tk_keys0 = tk_keys1 = tk_keys2 = nullptr;
        hipMemsetAsync(acc0, 0, (size_t)(N0c + N1c + N2c) * 32 * sizeof(float), stream);
        #define LIFT(Xp, Np, Wp) \
            gemm_lift<<<((Np) + 255) / 256, 256, 0, stream>>>((Xp), (Np), (Wp), Y)
        #define SPMM(rp, cp, vp, nz, accp) \
            spmm_kernel<<<((nz) * 8 + 255) / 256, 256, 0, stream>>>((rp), (cp), (vp), Y, (accp), (nz))
        LIFT(X0, N0c, W_n2n);  SPMM(L0r, L0c, L0v, nnzL0, acc0);
        LIFT(X0, N0c, W_n2e);  SPMM(D2r, D2c, D2v, nnzD2, acc1);
        LIFT(X1, N1c, W_e2e);  SPMM(L1r, L1c, L1v, nnzL1, acc1);
        LIFT(X1, N1c, W_e2n);  SPMM(D1r, D1c, D1v, nnzD1, acc0);
        LIFT(X1, N1c, W_e2t);  SPMM(B2r, B2c, B2v, nnzB2, acc2);
        LIFT(X2, N2c, W_t2t);  SPMM(L2r, L2c, L2v, nnzL2, acc2);
        LIFT(X2, N2c, W_t2e);  SPMM(B3r, B3c, B3v, nnzB3, acc1);
        #undef LIFT
        #undef SPMM
    }

    topk_conv_kernel<<<dim3(BG, 3), 256, 0, stream>>>(X0, X1, X2, acc0, acc1, acc2,
                                                      tk_keys0, tk_keys1, tk_keys2,
                                                      CWn, CWe, CWt, xfeat);
    mlp_stage1<<<dim3(BG, KSLICE), 256, 0, stream>>>(xfeat, MW1, hidp);
    mlp_stage2<<<BG, MLP_H, 0, stream>>>(hidp, MW2, (float*)d_out);
}

// Round 8
// 876.529 us; speedup vs baseline: 3.0823x; 1.0635x over previous
//
#include <hip/hip_runtime.h>

// ---------------- problem constants (fixed by reference) ----------------
#define N0c 128000
#define N1c 256000
#define N2c 128000
#define BG  64        // graphs per batch
#define KNc 30
#define KEc 60
#define KTc 30
#define COC 16        // conv out channels
#define MLP_IN 1920   // 16*(30+60+30)
#define MLP_H 128
#define KSLICE 8      // MLP stage-1 k-split
#define KCH (MLP_IN / KSLICE)   // 240

#define BINSHIFT 10           // 1024 rows per bin
#define BINROWS  1024
#define BDEPTH   16           // LDS staging depth per bin (pass 1)
#define BCAP     12288        // max entries per bin in pass 2 (mean ~8192)
#define CANDMAX  256          // topk radix-select candidate cap

typedef unsigned long long u64;
typedef unsigned int u32;

// ---------------------------------------------------------------------------
// K1: fused polynomial lift + dense GEMM.  Y[row] = [x, x*x] @ W   (64 -> 32)
// ---------------------------------------------------------------------------
__global__ __launch_bounds__(256) void gemm_lift(
    const float* __restrict__ X, int N, const float* __restrict__ W,
    float* __restrict__ Y)
{
    __shared__ float lw[2048];            // [64][32]
    const int tid = threadIdx.x;
    for (int i = tid; i < 2048; i += 256) lw[i] = W[i];
    __syncthreads();

    const int row = blockIdx.x * 256 + tid;
    if (row >= N) return;

    float x[64];
    const float4* p = reinterpret_cast<const float4*>(X + (size_t)row * 32);
    #pragma unroll
    for (int q = 0; q < 8; ++q) {
        float4 v = p[q];
        x[q*4+0] = v.x; x[q*4+1] = v.y; x[q*4+2] = v.z; x[q*4+3] = v.w;
    }
    #pragma unroll
    for (int i = 0; i < 32; ++i) x[32+i] = x[i] * x[i];

    const float4* lw4 = reinterpret_cast<const float4*>(lw);
    float4* yo = reinterpret_cast<float4*>(Y + (size_t)row * 32);
    #pragma unroll
    for (int j4 = 0; j4 < 8; ++j4) {
        float4 s = {0.f, 0.f, 0.f, 0.f};
        #pragma unroll
        for (int i = 0; i < 64; ++i) {
            float4 wf = lw4[i * 8 + j4];     // broadcast LDS read
            s.x = fmaf(x[i], wf.x, s.x);
            s.y = fmaf(x[i], wf.y, s.y);
            s.z = fmaf(x[i], wf.z, s.z);
            s.w = fmaf(x[i], wf.w, s.w);
        }
        yo[j4] = s;
    }
}

// ====================== binned CSR build (tier A) ===========================
__global__ __launch_bounds__(256) void bin_hist(
    const int* __restrict__ rows, int nnz, int epb, int nbins,
    int* __restrict__ bincnt)
{
    __shared__ int lh[256];
    const int tid = threadIdx.x;
    lh[tid] = 0;
    __syncthreads();
    const int base = blockIdx.x * epb;
    const int cnt = min(epb, nnz - base);
    for (int i = tid; i < cnt; i += 256)
        atomicAdd(&lh[rows[base + i] >> BINSHIFT], 1);
    __syncthreads();
    if (tid < nbins && lh[tid]) atomicAdd(&bincnt[tid], lh[tid]);
}

__global__ __launch_bounds__(256) void bin_scan(
    const int* __restrict__ bincnt, int nbins,
    int* __restrict__ binoff, int* __restrict__ gcur)
{
    __shared__ int sm[256];
    const int tid = threadIdx.x;
    const int v = (tid < nbins) ? bincnt[tid] : 0;
    sm[tid] = v;
    __syncthreads();
    for (int off = 1; off < 256; off <<= 1) {
        int t = (tid >= off) ? sm[tid - off] : 0;
        __syncthreads();
        sm[tid] += t;
        __syncthreads();
    }
    const int ex = sm[tid] - v;            // exclusive
    if (tid < nbins) { binoff[tid] = ex; gcur[tid] = ex; }
    if (tid == 255) binoff[nbins] = sm[255];
}

__global__ __launch_bounds__(256) void bin_scatter(
    const int* __restrict__ rows, const int* __restrict__ cols,
    const float* __restrict__ vals, int nnz, int epb, int nbins,
    int* __restrict__ gcur, u64* __restrict__ tmpP, u32* __restrict__ tmpR)
{
    __shared__ u64 bP[256 * BDEPTH];   // 32 KB
    __shared__ u32 bR[256 * BDEPTH];   // 16 KB
    __shared__ int lc[256];
    const int tid = threadIdx.x;
    lc[tid] = 0;
    __syncthreads();
    const int base = blockIdx.x * epb;
    const int cnt = min(epb, nnz - base);
    for (int i = tid; i < cnt; i += 256) {
        const int e = base + i;
        const int r = rows[e];
        const u64 pv = ((u64)__float_as_uint(vals[e]) << 32) | (u32)cols[e];
        const int b = r >> BINSHIFT;
        const int p = atomicAdd(&lc[b], 1);
        if (p < BDEPTH) {
            bP[b * BDEPTH + p] = pv;
            bR[b * BDEPTH + p] = (u32)r;
        } else {                               // rare spill (~1%)
            const int g = atomicAdd(&gcur[b], 1);
            tmpP[g] = pv; tmpR[g] = (u32)r;
        }
    }
    __syncthreads();
    if (tid < nbins) {
        int len = lc[tid]; if (len > BDEPTH) len = BDEPTH;
        if (len) {
            const int g = atomicAdd(&gcur[tid], len);
            for (int i = 0; i < len; ++i) {
                tmpP[g + i] = bP[tid * BDEPTH + i];
                tmpR[g + i] = bR[tid * BDEPTH + i];
            }
        }
    }
}

__global__ __launch_bounds__(256) void bin_build(
    const int* __restrict__ binoff, const u64* __restrict__ tmpP,
    const u32* __restrict__ tmpR, int R,
    u64* __restrict__ pairs, int* __restrict__ ptr)
{
    __shared__ unsigned short rl[BCAP];        // 24 KB
    __shared__ int h[BINROWS];                 // 4 KB
    __shared__ int cur[BINROWS];               // 4 KB
    __shared__ int sm[256];
    const int b = blockIdx.x, tid = threadIdx.x;
    const int base = binoff[b];
    int len = binoff[b + 1] - base;
    if (len > BCAP) len = BCAP;                // never expected

    for (int i = tid; i < BINROWS; i += 256) h[i] = 0;
    __syncthreads();
    for (int i = tid; i < len; i += 256) {
        const int r = (int)(tmpR[base + i] & (BINROWS - 1));
        rl[i] = (unsigned short)r;
        atomicAdd(&h[r], 1);
    }
    __syncthreads();

    const int i0 = tid * 4;
    const int a0 = h[i0], a1 = h[i0+1], a2 = h[i0+2], a3 = h[i0+3];
    const int s = a0 + a1 + a2 + a3;
    sm[tid] = s;
    __syncthreads();
    for (int off = 1; off < 256; off <<= 1) {
        int t = (tid >= off) ? sm[tid - off] : 0;
        __syncthreads();
        sm[tid] += t;
        __syncthreads();
    }
    const int run = sm[tid] - s;
    cur[i0]   = run;
    cur[i0+1] = run + a0;
    cur[i0+2] = run + a0 + a1;
    cur[i0+3] = run + a0 + a1 + a2;
    const int rstart = b << BINSHIFT;
    if (rstart + i0     < R) ptr[rstart + i0    ] = base + run + a0;
    if (rstart + i0 + 1 < R) ptr[rstart + i0 + 1] = base + run + a0 + a1;
    if (rstart + i0 + 2 < R) ptr[rstart + i0 + 2] = base + run + a0 + a1 + a2;
    if (rstart + i0 + 3 < R) ptr[rstart + i0 + 3] = base + run + a0 + a1 + a2 + a3;
    __syncthreads();

    for (int i = tid; i < len; i += 256) {
        const int r = rl[i];
        const int pos = base + atomicAdd(&cur[r], 1);
        pairs[pos] = tmpP[base + i];
    }
}

// ================== legacy CSR build kernels (tier B fallback) ==============
__global__ __launch_bounds__(256) void hist_kernel(
    const int* __restrict__ rows, int nnz, int* __restrict__ ptr)
{
    const int e = blockIdx.x * 256 + threadIdx.x;
    if (e < nnz) atomicAdd(&ptr[rows[e]], 1);
}

__global__ __launch_bounds__(256) void scan_reduce(
    const int* __restrict__ cnt, int n, int* __restrict__ bsum)
{
    __shared__ int sm[256];
    const int b = blockIdx.x, tid = threadIdx.x;
    const int base = b * 1024 + tid * 4;
    int s = 0;
    if (base + 3 < n) {
        int4 v = *reinterpret_cast<const int4*>(cnt + base);
        s = v.x + v.y + v.z + v.w;
    } else {
        for (int i = 0; i < 4; ++i) if (base + i < n) s += cnt[base + i];
    }
    sm[tid] = s; __syncthreads();
    #pragma unroll
    for (int st = 128; st > 0; st >>= 1) {
        if (tid < st) sm[tid] += sm[tid + st];
        __syncthreads();
    }
    if (tid == 0) bsum[b] = sm[0];
}

__global__ __launch_bounds__(1024) void scan_partials(int* __restrict__ bsum, int nb)
{
    __shared__ int sm[1024];
    const int tid = threadIdx.x;
    sm[tid] = (tid < nb) ? bsum[tid] : 0;
    __syncthreads();
    for (int off = 1; off < 1024; off <<= 1) {
        int v = (tid >= off) ? sm[tid - off] : 0;
        __syncthreads();
        sm[tid] += v;
        __syncthreads();
    }
    if (tid < nb) bsum[tid] = (tid == 0) ? 0 : sm[tid - 1];
}

__global__ __launch_bounds__(256) void scan_write(
    int* __restrict__ ptr, int n, const int* __restrict__ bsum)
{
    __shared__ int sm[256];
    const int b = blockIdx.x, tid = threadIdx.x;
    const int base = b * 1024 + tid * 4;
    int v[4]; int s = 0;
    #pragma unroll
    for (int i = 0; i < 4; ++i) {
        v[i] = (base + i < n) ? ptr[base + i] : 0;
        s += v[i];
    }
    sm[tid] = s; __syncthreads();
    for (int off = 1; off < 256; off <<= 1) {
        int t = (tid >= off) ? sm[tid - off] : 0;
        __syncthreads();
        sm[tid] += t;
        __syncthreads();
    }
    int run = bsum[b] + sm[tid] - s;
    #pragma unroll
    for (int i = 0; i < 4; ++i) {
        if (base + i < n) ptr[base + i] = run;
        run += v[i];
    }
}

__global__ __launch_bounds__(256) void scatter_kernel(
    const int* __restrict__ rows, const int* __restrict__ cols,
    const float* __restrict__ vals, int nnz,
    int* __restrict__ ptr, u64* __restrict__ pairs)
{
    const int e = blockIdx.x * 256 + threadIdx.x;
    if (e >= nnz) return;
    const int pos = atomicAdd(&ptr[rows[e]], 1);
    pairs[pos] = ((u64)__float_as_uint(vals[e]) << 32) | (u32)cols[e];
}

// ---------------------------------------------------------------------------
// K2': CSR gather SPMM.  8 lanes per row; lane j owns float4 chunk j.
// If keyout != null (final accumulate for this level), lane 7 also emits
// key[row] = kscale * relu(final col 31) -- fuses sortpool key extraction.
// ---------------------------------------------------------------------------
__global__ __launch_bounds__(256) void spmm_csr(
    const int* __restrict__ ptr, const u64* __restrict__ pairs,
    const float* __restrict__ Y, float* __restrict__ acc, int R, int STORE,
    float* __restrict__ keyout, float kscale)
{
    const int t = blockIdx.x * 256 + threadIdx.x;
    const int row = t >> 3;
    const int l8  = t & 7;
    if (row >= R) return;
    const int s = (row == 0) ? 0 : ptr[row - 1];
    const int e = ptr[row];

    const float4* Y4 = reinterpret_cast<const float4*>(Y);
    float4 a = {0.f, 0.f, 0.f, 0.f};
    for (int base = s; base < e; base += 8) {
        int m = e - base; if (m > 8) m = 8;
        u64 pk = (l8 < m) ? pairs[base + l8] : 0ULL;
        for (int j = 0; j < m; ++j) {
            const u64 pj = __shfl(pk, j, 8);
            const int col   = (int)(u32)(pj & 0xffffffffu);
            const float val = __uint_as_float((u32)(pj >> 32));
            const float4 y = Y4[(size_t)col * 8 + l8];
            a.x = fmaf(val, y.x, a.x); a.y = fmaf(val, y.y, a.y);
            a.z = fmaf(val, y.z, a.z); a.w = fmaf(val, y.w, a.w);
        }
    }
    float4* ap = reinterpret_cast<float4*>(acc) + (size_t)row * 8 + l8;
    float fin;
    if (STORE) {
        *ap = a;
        fin = a.w;
    } else {
        float4 o = *ap;
        o.x += a.x; o.y += a.y; o.z += a.z; o.w += a.w;
        *ap = o;
        fin = o.w;
    }
    if (keyout && l8 == 7)
        keyout[row] = kscale * fmaxf(fin, 0.0f);
}

// ---------------------------------------------------------------------------
// K2 (tier C fallback): atomic COO SPMM
// ---------------------------------------------------------------------------
__global__ __launch_bounds__(256) void spmm_kernel(
    const int* __restrict__ rows, const int* __restrict__ cols,
    const float* __restrict__ vals,
    const float* __restrict__ Y, float* __restrict__ acc, int nnz)
{
    const int t = blockIdx.x * 256 + threadIdx.x;
    const int e = t >> 3, c = t & 7;
    if (e >= nnz) return;
    const int r = rows[e], col = cols[e];
    const float v = vals[e];
    const float4 yv = reinterpret_cast<const float4*>(Y + (size_t)col * 32)[c];
    float* a = acc + (size_t)r * 32 + c * 4;
    unsafeAtomicAdd(a + 0, v * yv.x);
    unsafeAtomicAdd(a + 1, v * yv.y);
    unsafeAtomicAdd(a + 2, v * yv.z);
    unsafeAtomicAdd(a + 3, v * yv.w);
}

// ---------------------------------------------------------------------------
// K3: per (graph, level) top-k + pooled gather + conv1d(kernel=stride=64)+relu
// Top-k via radix-select: 2048-bin histogram of positive key bits (bits
// [31:20], monotone), suffix-scan for threshold bin, compact <=256 candidates,
// exact O(M^2/256) ranking.  Falls back to iterative argmax on degeneracy.
// ---------------------------------------------------------------------------
__global__ __launch_bounds__(256) void topk_conv_kernel(
    const float* __restrict__ X0, const float* __restrict__ X1,
    const float* __restrict__ X2,
    const float* __restrict__ acc0, const float* __restrict__ acc1,
    const float* __restrict__ acc2,
    const float* __restrict__ keys0, const float* __restrict__ keys1,
    const float* __restrict__ keys2,
    const float* __restrict__ CW0, const float* __restrict__ CW1,
    const float* __restrict__ CW2,
    float* __restrict__ xfeat)
{
    const int lvl = blockIdx.y;
    const int g   = blockIdx.x;
    int n, k, base; const float* X; const float* acc; const float* keys;
    const float* cw; float scale;
    if (lvl == 0)      { n = 2000; k = KNc; base = 0;             X = X0; acc = acc0; keys = keys0; cw = CW0; scale = 0.5f; }
    else if (lvl == 1) { n = 4000; k = KEc; base = COC*KNc;       X = X1; acc = acc1; keys = keys1; cw = CW1; scale = 1.0f/3.0f; }
    else               { n = 2000; k = KTc; base = COC*(KNc+KEc); X = X2; acc = acc2; keys = keys2; cw = CW2; scale = 0.5f; }

    __shared__ int  hist[2048];           // 8 KB
    __shared__ int  smi[256];
    __shared__ u64  cand[CANDMAX];        // 2 KB
    __shared__ u64  red[4];
    __shared__ float pooled[KEc][68];
    __shared__ float wt[64][16];
    __shared__ int  sel[KEc];
    __shared__ int  sT, mcur;

    const int tid = threadIdx.x;
    const size_t rowbase = (size_t)g * n;

    for (int i = tid; i < 2048; i += 256) hist[i] = 0;
    if (tid == 0) { sT = -1; mcur = 0; }
    __syncthreads();

    // load keys -> kreg (packed (kb<<32)|~r); histogram positive keys
    u64 kreg[16];
    #pragma unroll
    for (int i = 0; i < 16; ++i) {
        const int r = i * 256 + tid;
        u64 kk = 0ULL;
        if (r < n) {
            const float kv = keys ? keys[rowbase + r]
                                  : scale * fmaxf(acc[(rowbase + r) * 32 + 31], 0.0f);
            const u32 kb = (kv > 0.0f) ? __float_as_uint(kv) : 0u;  // kill -0.0
            kk = ((u64)kb << 32) | (u32)(~r);
            if (kb) atomicAdd(&hist[kb >> 20], 1);
        }
        kreg[i] = kk;
    }
    for (int i = tid; i < COC * 64; i += 256) wt[i & 63][i >> 6] = cw[i];
    __syncthreads();

    // per-thread sums over 8 owned bins + block inclusive scan
    int lb[8]; int ls = 0;
    #pragma unroll
    for (int i = 0; i < 8; ++i) { lb[i] = hist[tid * 8 + i]; ls += lb[i]; }
    smi[tid] = ls;
    __syncthreads();
    for (int off = 1; off < 256; off <<= 1) {
        int t = (tid >= off) ? smi[tid - off] : 0;
        __syncthreads();
        smi[tid] += t;
        __syncthreads();
    }
    const int total = smi[255];
    const int suf = total - smi[tid];      // keys in bins above this range
    if (total >= k && suf < k && suf + ls >= k) {   // unique crossing thread
        int c = suf;
        for (int i = 7; i >= 0; --i) {
            c += lb[i];
            if (c >= k) { sT = tid * 8 + i; break; }   // T = max bin, cnt>=k
        }
    }
    __syncthreads();

    bool fast = (sT >= 0);
    if (fast) {
        #pragma unroll
        for (int i = 0; i < 16; ++i) {
            const u32 kb = (u32)(kreg[i] >> 32);
            if (kb && (int)(kb >> 20) >= sT) {
                const int pos = atomicAdd(&mcur, 1);
                if (pos < CANDMAX) cand[pos] = kreg[i];
            }
        }
        __syncthreads();
        const int M = mcur;            // >= k by construction
        if (M <= CANDMAX) {
            for (int i = tid; i < M; i += 256) {
                const u64 e = cand[i];
                int rank = 0;
                for (int j = 0; j < M; ++j) rank += (cand[j] > e) ? 1 : 0;
                if (rank < k) sel[rank] = (int)(~(u32)e);
            }
        } else {
            fast = false;              // tie explosion -> fallback (uniform)
        }
    }
    __syncthreads();

    if (!fast) {
        // iterative argmax fallback (correct for all degenerate cases)
        for (int it = 0; it < k; ++it) {
            u64 m = 0ULL;
            #pragma unroll
            for (int i = 0; i < 16; ++i) m = kreg[i] > m ? kreg[i] : m;
            #pragma unroll
            for (int off = 32; off > 0; off >>= 1) {
                u64 o = __shfl_xor(m, off, 64);
                m = o > m ? o : m;
            }
            if ((tid & 63) == 0) red[tid >> 6] = m;
            __syncthreads();
            u64 m0 = red[0], m1 = red[1], m2 = red[2], m3 = red[3];
            u64 ma = m0 > m1 ? m0 : m1;
            u64 mb = m2 > m3 ? m2 : m3;
            u64 mm = ma > mb ? ma : mb;
            if (tid == 0) sel[it] = (int)(~(u32)mm);
            #pragma unroll
            for (int i = 0; i < 16; ++i) if (kreg[i] == mm) kreg[i] = 0ULL;
            __syncthreads();
        }
    }

    // gather pooled rows: [X_orig(32) | scale*relu(acc)(32)]
    for (int t = tid; t < k * 32; t += 256) {
        const int r = t >> 5, i = t & 31;
        const size_t row = rowbase + sel[r];
        pooled[r][i]      = X[row * 32 + i];
        pooled[r][32 + i] = scale * fmaxf(acc[row * 32 + i], 0.0f);
    }
    __syncthreads();

    float* xo = xfeat + (size_t)g * MLP_IN + base;
    for (int t = tid; t < k * COC; t += 256) {
        const int r = t >> 4, co = t & 15;
        float s = 0.f;
        #pragma unroll
        for (int j = 0; j < 64; ++j) s = fmaf(pooled[r][j], wt[j][co], s);
        xo[co * k + r] = fmaxf(s, 0.f);
    }
}

// ---------------------------------------------------------------------------
// K4a: MLP stage 1 (k-split).  Block (g, s): partial over 240 k's.
// ---------------------------------------------------------------------------
__global__ __launch_bounds__(256) void mlp_stage1(
    const float* __restrict__ xfeat, const float* __restrict__ W1,
    float* __restrict__ hidp)
{
    const int g = blockIdx.x, s = blockIdx.y;
    const int tid = threadIdx.x;
    const int j = tid & 127, half = tid >> 7;

    __shared__ float xs[KCH];
    __shared__ float red[256];
    if (tid < KCH) xs[tid] = xfeat[(size_t)g * MLP_IN + s * KCH + tid];
    __syncthreads();

    const float* w = W1 + (size_t)(s * KCH + half * (KCH/2)) * MLP_H + j;
    const float* xh = xs + half * (KCH/2);
    float a = 0.f;
    #pragma unroll 4
    for (int i = 0; i < KCH/2; ++i)
        a = fmaf(xh[i], w[(size_t)i * MLP_H], a);

    red[tid] = a;
    __syncthreads();
    if (half == 0)
        hidp[((size_t)g * KSLICE + s) * MLP_H + j] = red[j] + red[128 + j];
}

// ---------------------------------------------------------------------------
// K4b: MLP stage 2: hid = relu(sum partials); out = hid @ W2   (f32 out)
// ---------------------------------------------------------------------------
__global__ __launch_bounds__(128) void mlp_stage2(
    const float* __restrict__ hidp, const float* __restrict__ W2,
    float* __restrict__ out)
{
    const int g = blockIdx.x, j = threadIdx.x;
    float h = 0.f;
    #pragma unroll
    for (int s = 0; s < KSLICE; ++s)
        h += hidp[((size_t)g * KSLICE + s) * MLP_H + j];
    h = fmaxf(h, 0.f);
    __shared__ float hid[MLP_H];
    hid[j] = h;
    __syncthreads();
    if (j < 2) {
        float o = 0.f;
        #pragma unroll 8
        for (int t = 0; t < MLP_H; ++t) o = fmaf(hid[t], W2[t * 2 + j], o);
        out[g * 2 + j] = o;
    }
}

// ---------------------------------------------------------------------------
extern "C" void kernel_launch(void* const* d_in, const int* in_sizes, int n_in,
                              void* d_out, int out_size, void* d_ws, size_t ws_size,
                              hipStream_t stream)
{
    const int*   L0r = (const int*)d_in[0];
    const int*   L0c = (const int*)d_in[1];
    const float* L0v = (const float*)d_in[2];
    const int*   L1r = (const int*)d_in[3];
    const int*   L1c = (const int*)d_in[4];
    const float* L1v = (const float*)d_in[5];
    const int*   L2r = (const int*)d_in[6];
    const int*   L2c = (const int*)d_in[7];
    const float* L2v = (const float*)d_in[8];
    const int*   D1r = (const int*)d_in[9];    // D1invB1    (N0 x N1)
    const int*   D1c = (const int*)d_in[10];
    const float* D1v = (const float*)d_in[11];
    const int*   D2r = (const int*)d_in[12];   // D2B1TD1inv (N1 x N0)
    const int*   D2c = (const int*)d_in[13];
    const float* D2v = (const float*)d_in[14];
    const int*   B2r = (const int*)d_in[15];   // B2TD2inv   (N2 x N1)
    const int*   B2c = (const int*)d_in[16];
    const float* B2v = (const float*)d_in[17];
    const int*   B3r = (const int*)d_in[18];   // B2D3       (N1 x N2)
    const int*   B3c = (const int*)d_in[19];
    const float* B3v = (const float*)d_in[20];
    const float* X0  = (const float*)d_in[21];
    const float* X1  = (const float*)d_in[22];
    const float* X2  = (const float*)d_in[23];
    const float* W_n2n = (const float*)d_in[24];
    const float* W_n2e = (const float*)d_in[25];
    const float* W_e2e = (const float*)d_in[26];
    const float* W_e2n = (const float*)d_in[27];
    const float* W_e2t = (const float*)d_in[28];
    const float* W_t2e = (const float*)d_in[29];
    const float* W_t2t = (const float*)d_in[30];
    const float* CWn = (const float*)d_in[31];
    const float* CWe = (const float*)d_in[32];
    const float* CWt = (const float*)d_in[33];
    const float* MW1 = (const float*)d_in[34];
    const float* MW2 = (const float*)d_in[35];

    const int nnzL0 = in_sizes[0],  nnzL1 = in_sizes[3],  nnzL2 = in_sizes[6];
    const int nnzD1 = in_sizes[9],  nnzD2 = in_sizes[12];
    const int nnzB2 = in_sizes[15], nnzB3 = in_sizes[18];

    int maxnnz = nnzL0;
    if (nnzL1 > maxnnz) maxnnz = nnzL1;
    if (nnzL2 > maxnnz) maxnnz = nnzL2;
    if (nnzD1 > maxnnz) maxnnz = nnzD1;
    if (nnzD2 > maxnnz) maxnnz = nnzD2;
    if (nnzB2 > maxnnz) maxnnz = nnzB2;
    if (nnzB3 > maxnnz) maxnnz = nnzB3;

    // --- workspace layout (16B-aligned sections) ---
    char* wp = (char*)d_ws;
    #define WALLOC(ty, name, count) \
        ty* name = (ty*)wp; wp += (((size_t)(count) * sizeof(ty)) + 15) & ~(size_t)15;
    WALLOC(float, Y,     (size_t)N1c * 32)
    WALLOC(float, acc0,  (size_t)N0c * 32)
    WALLOC(float, acc1,  (size_t)N1c * 32)
    WALLOC(float, acc2,  (size_t)N2c * 32)
    WALLOC(float, xfeat, (size_t)BG * MLP_IN)
    WALLOC(float, hidp,  (size_t)BG * KSLICE * MLP_H)
    WALLOC(float, keys0, (size_t)N0c)
    WALLOC(float, keys1, (size_t)N1c)
    WALLOC(float, keys2, (size_t)N2c)
    WALLOC(u64,   pairs, (size_t)maxnnz)
    WALLOC(int,   ptr,   (size_t)N1c + 1)
    WALLOC(int,   bsum,  1024)
    const size_t need_B = (size_t)(wp - (char*)d_ws);
    WALLOC(u64,   tmpP,  (size_t)maxnnz)
    WALLOC(u32,   tmpR,  (size_t)maxnnz)
    WALLOC(int,   bincnt, 256 * 7)
    WALLOC(int,   binoff, 260)
    WALLOC(int,   gcur,   256)
    const size_t need_A = (size_t)(wp - (char*)d_ws);
    #undef WALLOC

    const float* tk_keys0 = keys0;
    const float* tk_keys1 = keys1;
    const float* tk_keys2 = keys2;

    if (ws_size >= need_A) {
        // ============ tier A: binned two-pass CSR build, no row atomics ======
        // one upfront memset for all 7 per-matrix bincnt slices
        hipMemsetAsync(bincnt, 0, 256 * 7 * sizeof(int), stream);
        #define BUILD_BIN(midx, rp, cp, vp, nz, R)                                    \
            do {                                                                       \
                const int nbins = ((R) + BINROWS - 1) / BINROWS;                       \
                const int epb = nbins * 8;                                             \
                const int nblk = ((nz) + epb - 1) / epb;                               \
                int* bc = bincnt + (midx) * 256;                                       \
                bin_hist<<<nblk, 256, 0, stream>>>((rp), (nz), epb, nbins, bc);        \
                bin_scan<<<1, 256, 0, stream>>>(bc, nbins, binoff, gcur);              \
                bin_scatter<<<nblk, 256, 0, stream>>>((rp), (cp), (vp), (nz), epb,     \
                                                      nbins, gcur, tmpP, tmpR);        \
                bin_build<<<nbins, 256, 0, stream>>>(binoff, tmpP, tmpR, (R),          \
                                                     pairs, ptr);                      \
            } while (0)
        #define LIFT(Xp, Np, Wp) \
            gemm_lift<<<((Np) + 255) / 256, 256, 0, stream>>>((Xp), (Np), (Wp), Y)
        #define SPMM_CSR(R, accp, store, keyp, ks) \
            spmm_csr<<<(((R) * 8) + 255) / 256, 256, 0, stream>>>(ptr, pairs, Y, (accp), (R), (store), (keyp), (ks))

        BUILD_BIN(0, L0r, L0c, L0v, nnzL0, N0c); LIFT(X0, N0c, W_n2n); SPMM_CSR(N0c, acc0, 1, (float*)0, 0.f);      // n2n
        BUILD_BIN(1, D2r, D2c, D2v, nnzD2, N1c); LIFT(X0, N0c, W_n2e); SPMM_CSR(N1c, acc1, 1, (float*)0, 0.f);      // n2e
        BUILD_BIN(2, L1r, L1c, L1v, nnzL1, N1c); LIFT(X1, N1c, W_e2e); SPMM_CSR(N1c, acc1, 0, (float*)0, 0.f);      // e2e
        BUILD_BIN(3, D1r, D1c, D1v, nnzD1, N0c); LIFT(X1, N1c, W_e2n); SPMM_CSR(N0c, acc0, 0, keys0, 0.5f);         // e2n (final acc0)
        BUILD_BIN(4, B2r, B2c, B2v, nnzB2, N2c); LIFT(X1, N1c, W_e2t); SPMM_CSR(N2c, acc2, 1, (float*)0, 0.f);      // e2t
        BUILD_BIN(5, L2r, L2c, L2v, nnzL2, N2c); LIFT(X2, N2c, W_t2t); SPMM_CSR(N2c, acc2, 0, keys2, 0.5f);         // t2t (final acc2)
        BUILD_BIN(6, B3r, B3c, B3v, nnzB3, N1c); LIFT(X2, N2c, W_t2e); SPMM_CSR(N1c, acc1, 0, keys1, 1.0f/3.0f);    // t2e (final acc1)

        #undef BUILD_BIN
        #undef LIFT
        #undef SPMM_CSR
    } else if (ws_size >= need_B) {
        // ============ tier B: CSR path (atomic scatter) ======================
        #define BUILD_CSR(rp, cp, vp, nz, R)                                         \
            do {                                                                      \
                hipMemsetAsync(ptr, 0, ((size_t)(R) + 1) * sizeof(int), stream);      \
                hist_kernel<<<((nz) + 255) / 256, 256, 0, stream>>>((rp), (nz), ptr); \
                const int nb = ((R) + 1023) / 1024;                                   \
                scan_reduce<<<nb, 256, 0, stream>>>(ptr, (R), bsum);                  \
                scan_partials<<<1, 1024, 0, stream>>>(bsum, nb);                      \
                scan_write<<<nb, 256, 0, stream>>>(ptr, (R), bsum);                   \
                scatter_kernel<<<((nz) + 255) / 256, 256, 0, stream>>>(               \
                    (rp), (cp), (vp), (nz), ptr, pairs);                              \
            } while (0)
        #define LIFT(Xp, Np, Wp) \
            gemm_lift<<<((Np) + 255) / 256, 256, 0, stream>>>((Xp), (Np), (Wp), Y)
        #define SPMM_CSR(R, accp, store, keyp, ks) \
            spmm_csr<<<(((R) * 8) + 255) / 256, 256, 0, stream>>>(ptr, pairs, Y, (accp), (R), (store), (keyp), (ks))

        BUILD_CSR(L0r, L0c, L0v, nnzL0, N0c); LIFT(X0, N0c, W_n2n); SPMM_CSR(N0c, acc0, 1, (float*)0, 0.f);
        BUILD_CSR(D2r, D2c, D2v, nnzD2, N1c); LIFT(X0, N0c, W_n2e); SPMM_CSR(N1c, acc1, 1, (float*)0, 0.f);
        BUILD_CSR(L1r, L1c, L1v, nnzL1, N1c); LIFT(X1, N1c, W_e2e); SPMM_CSR(N1c, acc1, 0, (float*)0, 0.f);
        BUILD_CSR(D1r, D1c, D1v, nnzD1, N0c); LIFT(X1, N1c, W_e2n); SPMM_CSR(N0c, acc0, 0, keys0, 0.5f);
        BUILD_CSR(B2r, B2c, B2v, nnzB2, N2c); LIFT(X1, N1c, W_e2t); SPMM_CSR(N2c, acc2, 1, (float*)0, 0.f);
        BUILD_CSR(L2r, L2c, L2v, nnzL2, N2c); LIFT(X2, N2c, W_t2t); SPMM_CSR(N2c, acc2, 0, keys2, 0.5f);
        BUILD_CSR(B3r, B3c, B3v, nnzB3, N1c); LIFT(X2, N2c, W_t2e); SPMM_CSR(N1c, acc1, 0, keys1, 1.0f/3.0f);

        #undef BUILD_CSR
        #undef LIFT
        #undef SPMM_CSR
    } else {
        // ============ tier C: atomic COO path (keys unavailable) =============
        tk_keys0 = tk_keys1 = tk_keys2 = nullptr;
        hipMemsetAsync(acc0, 0, (size_t)(N0c + N1c + N2c) * 32 * sizeof(float), stream);
        #define LIFT(Xp, Np, Wp) \
            gemm_lift<<<((Np) + 255) / 256, 256, 0, stream>>>((Xp), (Np), (Wp), Y)
        #define SPMM(rp, cp, vp, nz, accp) \
            spmm_kernel<<<((nz) * 8 + 255) / 256, 256, 0, stream>>>((rp), (cp), (vp), Y, (accp), (nz))
        LIFT(X0, N0c, W_n2n);  SPMM(L0r, L0c, L0v, nnzL0, acc0);
        LIFT(X0, N0c, W_n2e);  SPMM(D2r, D2c, D2v, nnzD2, acc1);
        LIFT(X1, N1c, W_e2e);  SPMM(L1r, L1c, L1v, nnzL1, acc1);
        LIFT(X1, N1c, W_e2n);  SPMM(D1r, D1c, D1v, nnzD1, acc0);
        LIFT(X1, N1c, W_e2t);  SPMM(B2r, B2c, B2v, nnzB2, acc2);
        LIFT(X2, N2c, W_t2t);  SPMM(L2r, L2c, L2v, nnzL2, acc2);
        LIFT(X2, N2c, W_t2e);  SPMM(B3r, B3c, B3v, nnzB3, acc1);
        #undef LIFT
        #undef SPMM
    }

    topk_conv_kernel<<<dim3(BG, 3), 256, 0, stream>>>(X0, X1, X2, acc0, acc1, acc2,
                                                      tk_keys0, tk_keys1, tk_keys2,
                                                      CWn, CWe, CWt, xfeat);
    mlp_stage1<<<dim3(BG, KSLICE), 256, 0, stream>>>(xfeat, MW1, hidp);
    mlp_stage2<<<BG, MLP_H, 0, stream>>>(hidp, MW2, (float*)d_out);
}